// Round 3
// baseline (2234.313 us; speedup 1.0000x reference)
//
#include <hip/hip_runtime.h>
#include <cstdint>
#include <cstddef>

// CrossAttention1d: N=4, C=512, S=2048, CTX=512, S2=2048, H=8
// R3: flash PV d-split across waves (LDS traffic -31%), split-K out GEMM w/
// atomics, LDS-transposed coalesced epilogues for qT/kT, templated K loop.

#define NB 4
#define CC 512
#define SS 2048
#define HH 8
#define QK_SCALE 0.044194173824159216f  // 512^-0.5

typedef float  floatx4 __attribute__((ext_vector_type(4)));
typedef __bf16 bf16x8  __attribute__((ext_vector_type(8)));
typedef __bf16 bf16x4  __attribute__((ext_vector_type(4)));

__device__ __forceinline__ void async16(const void* g, void* l) {
  __builtin_amdgcn_global_load_lds((const __attribute__((address_space(1))) void*)g,
                                   (__attribute__((address_space(3))) void*)l, 16, 0, 0);
}

// ---------------- LayerNorm stats ----------------
__global__ void ln_partial(const float* __restrict__ x, float* __restrict__ part) {
  const int n = blockIdx.x >> 7, cidx = blockIdx.x & 127;
  const float* p = x + (size_t)n * (CC * SS) + (size_t)cidx * 8192;
  float s = 0.f, q = 0.f;
  for (int j = 0; j < 8; ++j) {
    floatx4 v = *(const floatx4*)&p[(j * 256 + threadIdx.x) * 4];
    for (int e = 0; e < 4; ++e) { s += v[e]; q += v[e] * v[e]; }
  }
  for (int off = 32; off >= 1; off >>= 1) {
    s += __shfl_down(s, off, 64);
    q += __shfl_down(q, off, 64);
  }
  __shared__ float shS[4], shQ[4];
  const int wave = threadIdx.x >> 6, lane = threadIdx.x & 63;
  if (lane == 0) { shS[wave] = s; shQ[wave] = q; }
  __syncthreads();
  if (threadIdx.x == 0) {
    part[blockIdx.x * 2] = shS[0] + shS[1] + shS[2] + shS[3];
    part[blockIdx.x * 2 + 1] = shQ[0] + shQ[1] + shQ[2] + shQ[3];
  }
}

__global__ void ln_final(const float* __restrict__ part, float* __restrict__ muA,
                         float* __restrict__ rsA) {
  const int n = blockIdx.x, tid = threadIdx.x;
  float s = part[(n * 128 + tid) * 2];
  float q = part[(n * 128 + tid) * 2 + 1];
  for (int off = 32; off >= 1; off >>= 1) {
    s += __shfl_down(s, off, 64);
    q += __shfl_down(q, off, 64);
  }
  __shared__ float shS[2], shQ[2];
  const int wave = tid >> 6, lane = tid & 63;
  if (lane == 0) { shS[wave] = s; shQ[wave] = q; }
  __syncthreads();
  if (tid == 0) {
    float S = shS[0] + shS[1], Q = shQ[0] + shQ[1];
    const float inv = 1.f / (float)(CC * SS);
    float m = S * inv;
    float v = Q * inv - m * m;
    muA[n] = m;
    rsA[n] = rsqrtf(v + 1e-5f);
  }
}

// ---------------- weight cast fp32 -> bf16 ----------------
__global__ void cast_w(const float* __restrict__ w, __bf16* __restrict__ o, int n4) {
  int idx = blockIdx.x * 256 + threadIdx.x;
  if (idx >= n4) return;
  floatx4 v = ((const floatx4*)w)[idx];
  bf16x4 pk;
  for (int e = 0; e < 4; ++e) pk[e] = (__bf16)v[e];
  ((bf16x4*)o)[idx] = pk;
}

// ---------------- normalize (optional) + transpose bf16 ----------------
__global__ void transpose_norm(const float* __restrict__ in, __bf16* __restrict__ out,
                               const float* __restrict__ mu, const float* __restrict__ rstd,
                               const float* __restrict__ gamma, const float* __restrict__ beta) {
  __shared__ float t[32][33];
  const int n = blockIdx.z;
  const int c0 = blockIdx.y * 32, s0 = blockIdx.x * 32;
  const float muv = mu ? mu[n] : 0.f;
  const float rs = rstd ? rstd[n] : 1.f;
  const float* inp = in + (size_t)n * CC * SS;
  for (int i = 0; i < 4; ++i) {
    int c = c0 + threadIdx.y + i * 8;
    float x = inp[(size_t)c * SS + s0 + threadIdx.x];
    if (gamma) x = (x - muv) * rs * gamma[c] + beta[c];
    t[threadIdx.y + i * 8][threadIdx.x] = x;
  }
  __syncthreads();
  __bf16* op = out + (size_t)n * SS * CC;
  for (int i = 0; i < 4; ++i) {
    int s = s0 + threadIdx.y + i * 8;
    op[(size_t)s * CC + c0 + threadIdx.x] = (__bf16)t[threadIdx.x][threadIdx.y + i * 8];
  }
}

// ---------------- out init: out = input + bo[c] ----------------
__global__ void out_init(const float* __restrict__ input, const float* __restrict__ bo,
                         float* __restrict__ out) {
  size_t e = ((size_t)blockIdx.x * 256 + threadIdx.x) * 4;
  int c = (int)((e >> 11) & 511);
  floatx4 v = *(const floatx4*)&input[e];
  float b = bo[c];
  floatx4 o;
  for (int i = 0; i < 4; ++i) o[i] = v[i] + b;
  *(floatx4*)&out[e] = o;
}

// ---------------- GEMM mainloop: C(128x128) = A(MxK,row,lda) * Bt(NxK,row,ldb)^T ----------------
template <int KT>
__device__ __forceinline__ void gemm_tile(const __bf16* __restrict__ A,
                                          const __bf16* __restrict__ Bt, int lda, int ldb,
                                          int m0, int n0, __bf16* ldsA, __bf16* ldsB,
                                          floatx4 acc[4][4]) {
  const int tid = threadIdx.x;
  const int wave = tid >> 6, lane = tid & 63;
  const int colv = lane & 15, g = lane >> 4;
  const int wm = wave & 1, wn = wave >> 1;
  const int lrow = lane >> 3, lch = lane & 7;

#pragma unroll
  for (int mt = 0; mt < 4; ++mt)
#pragma unroll
    for (int nt = 0; nt < 4; ++nt) acc[mt][nt] = (floatx4)0.f;

  for (int k0 = 0; k0 < KT; k0 += 64) {
    __syncthreads();
#pragma unroll
    for (int j = 0; j < 4; ++j) {
      int r = wave * 32 + j * 8 + lrow;
      int ch = lch ^ (r & 7);
      async16(A + (size_t)(m0 + r) * lda + k0 + ch * 8, &ldsA[(wave * 32 + j * 8) * 64]);
      async16(Bt + (size_t)(n0 + r) * ldb + k0 + ch * 8, &ldsB[(wave * 32 + j * 8) * 64]);
    }
    __syncthreads();
#pragma unroll
    for (int c = 0; c < 2; ++c) {
      bf16x8 af[4], bf[4];
#pragma unroll
      for (int t = 0; t < 4; ++t) {
        int r = wm * 64 + t * 16 + colv;
        af[t] = *(const bf16x8*)&ldsA[r * 64 + (((c * 4 + g) ^ (r & 7)) << 3)];
        int rb = wn * 64 + t * 16 + colv;
        bf[t] = *(const bf16x8*)&ldsB[rb * 64 + (((c * 4 + g) ^ (rb & 7)) << 3)];
      }
#pragma unroll
      for (int mt = 0; mt < 4; ++mt)
#pragma unroll
        for (int nt = 0; nt < 4; ++nt)
          acc[mt][nt] = __builtin_amdgcn_mfma_f32_16x16x32_bf16(af[mt], bf[nt], acc[mt][nt], 0, 0, 0);
    }
  }
}

// Coalesced epilogue: stage C (+bias, cast bf16) into LDS as [n_local][m_local],
// then write rows of the M-contiguous output  dst[(n0+nl)*ldd + m0+ml].
__device__ __forceinline__ void epilogue_store_T(floatx4 acc[4][4], const float* __restrict__ bias,
                                                 int m0, int n0, __bf16* lds, __bf16* dst,
                                                 int ldd) {
  const int tid = threadIdx.x;
  const int wave = tid >> 6, lane = tid & 63;
  const int colv = lane & 15, g = lane >> 4;
  const int wm = wave & 1, wn = wave >> 1;
  __syncthreads();  // mainloop LDS reads done
#pragma unroll
  for (int mt = 0; mt < 4; ++mt) {
    int o = m0 + wm * 64 + mt * 16 + g * 4;
    floatx4 bv = *(const floatx4*)&bias[o];
#pragma unroll
    for (int nt = 0; nt < 4; ++nt) {
      int nl = wn * 64 + nt * 16 + colv;
      int ml = wm * 64 + mt * 16 + g * 4;
#pragma unroll
      for (int i = 0; i < 4; ++i)
        lds[nl * 128 + ml + i] = (__bf16)(acc[mt][nt][i] + bv[i]);
    }
  }
  __syncthreads();
#pragma unroll
  for (int p = 0; p < 8; ++p) {
    int nl = p * 16 + (tid >> 4);
    bf16x8 v = *(const bf16x8*)&lds[nl * 128 + (tid & 15) * 8];
    *(bf16x8*)&dst[(size_t)(n0 + nl) * ldd + m0 + (tid & 15) * 8] = v;
  }
}

// ---------------- GEMM 1: qT[n](2048x4096) = (Wq*xn)^T + bq ----------------
__global__ void __launch_bounds__(256) gemm_q(const __bf16* __restrict__ Wq,
                                              const __bf16* __restrict__ xnT,
                                              const float* __restrict__ bq,
                                              __bf16* __restrict__ qT) {
  __shared__ __bf16 lA[128 * 64], lB[128 * 64];
  const int n = blockIdx.z;
  const int m0 = blockIdx.x * 128, n0 = blockIdx.y * 128;
  floatx4 acc[4][4];
  gemm_tile<512>(Wq, xnT + (size_t)n * SS * CC, 512, 512, m0, n0, lA, lB, acc);
  epilogue_store_T(acc, bq, m0, n0, lA, qT + (size_t)n * SS * 4096, 4096);
}

// ---------------- GEMM 2: kv; K-half -> kT, V-half -> v (d-major) ----------------
__global__ void __launch_bounds__(256) gemm_kv(const __bf16* __restrict__ Wkv,
                                               const __bf16* __restrict__ ctxT,
                                               const float* __restrict__ bkv,
                                               __bf16* __restrict__ kT,
                                               __bf16* __restrict__ vv) {
  __shared__ __bf16 lA[128 * 64], lB[128 * 64];
  const int n = blockIdx.z;
  const int m0 = blockIdx.x * 128, n0 = blockIdx.y * 128;
  floatx4 acc[4][4];
  gemm_tile<512>(Wkv, ctxT + (size_t)n * SS * CC, 512, 512, m0, n0, lA, lB, acc);
  const int lane = threadIdx.x & 63, wave = threadIdx.x >> 6;
  const int colv = lane & 15, g = lane >> 4;
  const int wm = wave & 1, wn = wave >> 1;
  if (m0 < 4096) {
    epilogue_store_T(acc, bkv, m0, n0, lA, kT + (size_t)n * SS * 4096, 4096);
  } else {
    __bf16* vn = vv + (size_t)n * 4096 * SS;
#pragma unroll
    for (int mt = 0; mt < 4; ++mt) {
      int o = m0 + wm * 64 + mt * 16 + g * 4;
      floatx4 bias = *(const floatx4*)&bkv[o];
#pragma unroll
      for (int nt = 0; nt < 4; ++nt) {
        int s = n0 + wn * 64 + nt * 16 + colv;
#pragma unroll
        for (int i = 0; i < 4; ++i)
          vn[(size_t)(o + i - 4096) * SS + s] = (__bf16)(acc[mt][nt][i] + bias[i]);
      }
    }
  }
}

// ---------------- flash attention (PV d-split across waves) ----------------
// grid (S/64, H, nb); block 256 = 4 waves. Scores/softmax: wave w owns queries
// [qt*64 + w*16, +16). PV: wave w computes ALL 64 queries over d-slice w*128.
__global__ void __launch_bounds__(256, 2) flash_attn(const __bf16* __restrict__ qT,
                                                     const __bf16* __restrict__ kT,
                                                     const __bf16* __restrict__ vv,
                                                     __bf16* __restrict__ yT) {
  const int n = blockIdx.z, h = blockIdx.y, qt = blockIdx.x;
  const int tid = threadIdx.x;
  const int wave = tid >> 6, lane = tid & 63;
  const int colv = lane & 15, g = lane >> 4;

  const __bf16* qTn = qT + (size_t)n * SS * 4096;
  const __bf16* kTn = kT + (size_t)n * SS * 4096;
  const __bf16* vn  = vv + (size_t)n * 4096 * SS;
  __bf16* yTn = yT + (size_t)n * SS * 4096;

  const int qrow0 = qt * 64 + wave * 16;  // owned for scores/softmax

  __shared__ __bf16 kbuf[32 * 512];  // row = key, xor-swizzled chunks
  __shared__ __bf16 vbuf[512 * 32];  // row = d
  __shared__ float axs[64];          // per-query alpha (per kt) / 1/l (epilogue)

  bf16x8 qf[16];
  {
    const __bf16* qp = qTn + (size_t)(qrow0 + colv) * 4096 + h * 512 + g * 8;
#pragma unroll
    for (int kc = 0; kc < 16; ++kc) qf[kc] = *(const bf16x8*)(qp + kc * 32);
  }

  // Oacc[qt4*8+dt]: rows qt4*16.., cols wave*128 + dt*16..
  floatx4 Oacc[32];
#pragma unroll
  for (int t = 0; t < 32; ++t) Oacc[t] = (floatx4)0.f;
  float mrun[4] = {-1e30f, -1e30f, -1e30f, -1e30f};
  float lrun[4] = {0.f, 0.f, 0.f, 0.f};

  // P staging aliased into kbuf rows 0..11 (written after (c), read before next (a))
  __bf16* pb = kbuf + wave * (16 * 88);

  for (int kt = 0; kt < 64; ++kt) {
    const int key0 = kt * 32;
    __syncthreads();  // (a) prior tile's LDS reads done
#pragma unroll
    for (int j = 0; j < 8; ++j) {
      int row = wave * 8 + j;
      const __bf16* src = kTn + (size_t)(key0 + row) * 4096 + h * 512 + ((lane ^ (row & 7)) << 3);
      async16(src, &kbuf[row * 512]);
    }
#pragma unroll
    for (int j = 0; j < 8; ++j) {
      int i = wave * 8 + j;
      int row = i * 16 + (lane >> 2);
      int ch = (lane & 3) ^ (row & 3);
      const __bf16* src = vn + (size_t)(h * 512 + row) * SS + key0 + ch * 8;
      async16(src, &vbuf[i * 16 * 32]);
    }
    __syncthreads();  // (b) staging complete

    floatx4 sc[2];
    sc[0] = (floatx4)0.f;
    sc[1] = (floatx4)0.f;
#pragma unroll
    for (int ct = 0; ct < 2; ++ct) {
      int key = ct * 16 + colv;
      const __bf16* kb = &kbuf[key * 512];
      int sw = key & 7;
#pragma unroll
      for (int kc = 0; kc < 16; ++kc) {
        bf16x8 bfr = *(const bf16x8*)(kb + (((kc * 4 + g) ^ sw) << 3));
        sc[ct] = __builtin_amdgcn_mfma_f32_16x16x32_bf16(qf[kc], bfr, sc[ct], 0, 0, 0);
      }
    }
    __syncthreads();  // (c) kbuf score reads done -> P region writable

    float p[2][4], alpha[4];
#pragma unroll
    for (int i = 0; i < 4; ++i) {
      float mx = fmaxf(sc[0][i], sc[1][i]);
#pragma unroll
      for (int off = 8; off >= 1; off >>= 1) mx = fmaxf(mx, __shfl_xor(mx, off, 64));
      float mnew = fmaxf(mrun[i], mx * QK_SCALE);
      alpha[i] = __expf(mrun[i] - mnew);
      float rs = 0.f;
#pragma unroll
      for (int ct = 0; ct < 2; ++ct) {
        float pvv = __expf(sc[ct][i] * QK_SCALE - mnew);
        p[ct][i] = pvv;
        rs += pvv;
      }
#pragma unroll
      for (int off = 8; off >= 1; off >>= 1) rs += __shfl_xor(rs, off, 64);
      lrun[i] = lrun[i] * alpha[i] + rs;
      mrun[i] = mnew;
    }
#pragma unroll
    for (int ct = 0; ct < 2; ++ct)
#pragma unroll
      for (int i = 0; i < 4; ++i)
        pb[(g * 4 + i) * 88 + ct * 16 + colv] = (__bf16)p[ct][i];
    if (colv == 0) {
      floatx4 av;
#pragma unroll
      for (int i = 0; i < 4; ++i) av[i] = alpha[i];
      *(floatx4*)&axs[wave * 16 + g * 4] = av;
    }
    __syncthreads();  // (d) P + alpha visible to all waves

    // rescale O (rows qt4-tile scaled by owning wave's alpha)
#pragma unroll
    for (int qt4 = 0; qt4 < 4; ++qt4) {
      floatx4 av = *(const floatx4*)&axs[qt4 * 16 + g * 4];
#pragma unroll
      for (int dt = 0; dt < 8; ++dt) {
        floatx4 o = Oacc[qt4 * 8 + dt];
#pragma unroll
        for (int i = 0; i < 4; ++i) o[i] *= av[i];
        Oacc[qt4 * 8 + dt] = o;
      }
    }
    // PV: A = P (4 query tiles), B = V slice d in [wave*128, +128)
    bf16x8 pa[4];
#pragma unroll
    for (int qt4 = 0; qt4 < 4; ++qt4)
      pa[qt4] = *(const bf16x8*)&kbuf[qt4 * (16 * 88) + colv * 88 + g * 8];
#pragma unroll
    for (int dt = 0; dt < 8; ++dt) {
      int drow = wave * 128 + dt * 16 + colv;
      bf16x8 vb = *(const bf16x8*)&vbuf[drow * 32 + ((g ^ (drow & 3)) << 3)];
#pragma unroll
      for (int qt4 = 0; qt4 < 4; ++qt4)
        Oacc[qt4 * 8 + dt] = __builtin_amdgcn_mfma_f32_16x16x32_bf16(pa[qt4], vb,
                                                                    Oacc[qt4 * 8 + dt], 0, 0, 0);
    }
  }

  if (colv == 0) {
    floatx4 lv;
#pragma unroll
    for (int i = 0; i < 4; ++i) lv[i] = 1.f / lrun[i];
    *(floatx4*)&axs[wave * 16 + g * 4] = lv;
  }
  __syncthreads();
#pragma unroll
  for (int qt4 = 0; qt4 < 4; ++qt4) {
    floatx4 lv = *(const floatx4*)&axs[qt4 * 16 + g * 4];
#pragma unroll
    for (int dt = 0; dt < 8; ++dt)
#pragma unroll
      for (int i = 0; i < 4; ++i) {
        size_t idx = (size_t)(qt * 64 + qt4 * 16 + g * 4 + i) * 4096 + h * 512 + wave * 128 +
                     dt * 16 + colv;
        yTn[idx] = (__bf16)(Oacc[qt4 * 8 + dt][i] * lv[i]);
      }
  }
}

// ---------------- GEMM 3 (split-K, atomic): out += Wo*y ----------------
// A = yT (M=2048=s, K=4096), Bt = Wo (N=512=c, K=4096); K split into 4x1024.
__global__ void __launch_bounds__(256) gemm_out_atomic(const __bf16* __restrict__ yT,
                                                       const __bf16* __restrict__ Wo,
                                                       float* __restrict__ out, int nfix) {
  __shared__ __bf16 lA[128 * 64], lB[128 * 64];
  int n, kz;
  if (nfix >= 0) { n = nfix; kz = blockIdx.z; }
  else { n = blockIdx.z & 3; kz = blockIdx.z >> 2; }
  const int m0 = blockIdx.x * 128, n0 = blockIdx.y * 128;
  floatx4 acc[4][4];
  gemm_tile<1024>(yT + (size_t)n * SS * 4096 + kz * 1024, Wo + kz * 1024, 4096, 4096, m0, n0,
                  lA, lB, acc);
  const int lane = threadIdx.x & 63, wave = threadIdx.x >> 6;
  const int colv = lane & 15, g = lane >> 4;
  const int wm = wave & 1, wn = wave >> 1;
#pragma unroll
  for (int mt = 0; mt < 4; ++mt) {
    int srow = m0 + wm * 64 + mt * 16 + g * 4;
#pragma unroll
    for (int nt = 0; nt < 4; ++nt) {
      int ccol = n0 + wn * 64 + nt * 16 + colv;
      size_t base = ((size_t)n * CC + ccol) * SS + srow;
#pragma unroll
      for (int i = 0; i < 4; ++i) atomicAdd(&out[base + i], acc[mt][nt][i]);
    }
  }
}

// ---------------- host launcher ----------------
extern "C" void kernel_launch(void* const* d_in, const int* in_sizes, int n_in,
                              void* d_out, int out_size, void* d_ws, size_t ws_size,
                              hipStream_t stream) {
  const float* input   = (const float*)d_in[0];
  const float* context = (const float*)d_in[1];
  const float* gamma   = (const float*)d_in[2];
  const float* beta    = (const float*)d_in[3];
  const float* Wq      = (const float*)d_in[4];
  const float* bq      = (const float*)d_in[5];
  const float* Wkv     = (const float*)d_in[6];
  const float* bkv     = (const float*)d_in[7];
  const float* Wo      = (const float*)d_in[8];
  const float* bo      = (const float*)d_in[9];
  float* out = (float*)d_out;
  (void)in_sizes; (void)n_in; (void)out_size;

  char* ws = (char*)d_ws;
  size_t off = 0;
  auto alloc = [&](size_t b) {
    void* p = ws + off;
    off = (off + b + 255) & ~(size_t)255;
    return p;
  };
  float*  part = (float*)alloc((size_t)4 * 128 * 2 * sizeof(float));
  float*  muA  = (float*)alloc(4 * sizeof(float));
  float*  rsA  = (float*)alloc(4 * sizeof(float));
  __bf16* WqB  = (__bf16*)alloc((size_t)4096 * 512 * 2);
  __bf16* WkvB = (__bf16*)alloc((size_t)8192 * 512 * 2);
  __bf16* WoB  = (__bf16*)alloc((size_t)512 * 4096 * 2);
  __bf16* xnT  = (__bf16*)alloc((size_t)NB * SS * CC * 2);
  __bf16* ctxT = (__bf16*)alloc((size_t)NB * SS * CC * 2);

  const size_t PB = (size_t)SS * 4096 * 2;  // 16 MB per batch of q/k/v/y

  ln_partial<<<dim3(512), dim3(256), 0, stream>>>(input, part);
  ln_final<<<dim3(4), dim3(128), 0, stream>>>(part, muA, rsA);
  cast_w<<<dim3(2048), dim3(256), 0, stream>>>(Wq, WqB, 524288);
  cast_w<<<dim3(4096), dim3(256), 0, stream>>>(Wkv, WkvB, 1048576);
  cast_w<<<dim3(2048), dim3(256), 0, stream>>>(Wo, WoB, 524288);
  transpose_norm<<<dim3(64, 16, 4), dim3(32, 8), 0, stream>>>(input, xnT, muA, rsA, gamma, beta);
  transpose_norm<<<dim3(64, 16, 4), dim3(32, 8), 0, stream>>>(context, ctxT, nullptr, nullptr,
                                                              nullptr, nullptr);
  out_init<<<dim3(4096), dim3(256), 0, stream>>>(input, bo, out);

  const size_t MiB = 1ull << 20;
  if (ws_size >= off + 16 * PB + 8 * MiB) {
    // Path A: full-batch buffers
    __bf16* qTb = (__bf16*)alloc(NB * PB);
    __bf16* kTb = (__bf16*)alloc(NB * PB);
    __bf16* vB  = (__bf16*)alloc(NB * PB);
    __bf16* yTb = (__bf16*)alloc(NB * PB);
    gemm_q<<<dim3(32, 16, 4), dim3(256), 0, stream>>>(WqB, xnT, bq, qTb);
    gemm_kv<<<dim3(64, 16, 4), dim3(256), 0, stream>>>(WkvB, ctxT, bkv, kTb, vB);
    flash_attn<<<dim3(32, 8, 4), dim3(256), 0, stream>>>(qTb, kTb, vB, yTb);
    gemm_out_atomic<<<dim3(16, 4, 16), dim3(256), 0, stream>>>(yTb, WoB, out, -1);
  } else if (ws_size >= off + 7 * PB + 8 * MiB) {
    // Path B: per-batch q/k/v, full yT
    __bf16* qTb = (__bf16*)alloc(PB);
    __bf16* kTb = (__bf16*)alloc(PB);
    __bf16* vB  = (__bf16*)alloc(PB);
    __bf16* yTb = (__bf16*)alloc(NB * PB);
    for (int n = 0; n < NB; ++n) {
      gemm_q<<<dim3(32, 16, 1), dim3(256), 0, stream>>>(WqB, xnT + (size_t)n * SS * CC, bq, qTb);
      gemm_kv<<<dim3(64, 16, 1), dim3(256), 0, stream>>>(WkvB, ctxT + (size_t)n * SS * CC, bkv,
                                                         kTb, vB);
      flash_attn<<<dim3(32, 8, 1), dim3(256), 0, stream>>>(qTb, kTb, vB,
                                                           yTb + (size_t)n * SS * 4096);
    }
    gemm_out_atomic<<<dim3(16, 4, 16), dim3(256), 0, stream>>>(yTb, WoB, out, -1);
  } else {
    // Path C: everything per-batch
    __bf16* qTb = (__bf16*)alloc(PB);
    __bf16* kTb = (__bf16*)alloc(PB);
    __bf16* vB  = (__bf16*)alloc(PB);
    __bf16* yTb = (__bf16*)alloc(PB);
    for (int n = 0; n < NB; ++n) {
      gemm_q<<<dim3(32, 16, 1), dim3(256), 0, stream>>>(WqB, xnT + (size_t)n * SS * CC, bq, qTb);
      gemm_kv<<<dim3(64, 16, 1), dim3(256), 0, stream>>>(WkvB, ctxT + (size_t)n * SS * CC, bkv,
                                                         kTb, vB);
      flash_attn<<<dim3(32, 8, 1), dim3(256), 0, stream>>>(qTb, kTb, vB, yTb);
      gemm_out_atomic<<<dim3(16, 4, 4), dim3(256), 0, stream>>>(yTb, WoB, out, n);
    }
  }
}

// Round 4
// 1265.111 us; speedup vs baseline: 1.7661x; 1.7661x over previous
//
#include <hip/hip_runtime.h>
#include <cstdint>
#include <cstddef>

// CrossAttention1d: N=4, C=512, S=2048, CTX=512, S2=2048, H=8
// R4: un-spill flash (no min-waves launch_bounds cap; R3's cap=128 VGPR caused
// 204MB/dispatch scratch writes), dedicated P-staging LDS (3 barriers/kt),
// split-K=2 out GEMM into fp32 partials + vector combine (no dword atomics).

#define NB 4
#define CC 512
#define SS 2048
#define HH 8
#define QK_SCALE 0.044194173824159216f  // 512^-0.5

typedef float  floatx4 __attribute__((ext_vector_type(4)));
typedef __bf16 bf16x8  __attribute__((ext_vector_type(8)));
typedef __bf16 bf16x4  __attribute__((ext_vector_type(4)));

__device__ __forceinline__ void async16(const void* g, void* l) {
  __builtin_amdgcn_global_load_lds((const __attribute__((address_space(1))) void*)g,
                                   (__attribute__((address_space(3))) void*)l, 16, 0, 0);
}

// ---------------- LayerNorm stats ----------------
__global__ void ln_partial(const float* __restrict__ x, float* __restrict__ part) {
  const int n = blockIdx.x >> 7, cidx = blockIdx.x & 127;
  const float* p = x + (size_t)n * (CC * SS) + (size_t)cidx * 8192;
  float s = 0.f, q = 0.f;
  for (int j = 0; j < 8; ++j) {
    floatx4 v = *(const floatx4*)&p[(j * 256 + threadIdx.x) * 4];
    for (int e = 0; e < 4; ++e) { s += v[e]; q += v[e] * v[e]; }
  }
  for (int off = 32; off >= 1; off >>= 1) {
    s += __shfl_down(s, off, 64);
    q += __shfl_down(q, off, 64);
  }
  __shared__ float shS[4], shQ[4];
  const int wave = threadIdx.x >> 6, lane = threadIdx.x & 63;
  if (lane == 0) { shS[wave] = s; shQ[wave] = q; }
  __syncthreads();
  if (threadIdx.x == 0) {
    part[blockIdx.x * 2] = shS[0] + shS[1] + shS[2] + shS[3];
    part[blockIdx.x * 2 + 1] = shQ[0] + shQ[1] + shQ[2] + shQ[3];
  }
}

__global__ void ln_final(const float* __restrict__ part, float* __restrict__ muA,
                         float* __restrict__ rsA) {
  const int n = blockIdx.x, tid = threadIdx.x;
  float s = part[(n * 128 + tid) * 2];
  float q = part[(n * 128 + tid) * 2 + 1];
  for (int off = 32; off >= 1; off >>= 1) {
    s += __shfl_down(s, off, 64);
    q += __shfl_down(q, off, 64);
  }
  __shared__ float shS[2], shQ[2];
  const int wave = tid >> 6, lane = tid & 63;
  if (lane == 0) { shS[wave] = s; shQ[wave] = q; }
  __syncthreads();
  if (tid == 0) {
    float S = shS[0] + shS[1], Q = shQ[0] + shQ[1];
    const float inv = 1.f / (float)(CC * SS);
    float m = S * inv;
    float v = Q * inv - m * m;
    muA[n] = m;
    rsA[n] = rsqrtf(v + 1e-5f);
  }
}

// ---------------- weight cast fp32 -> bf16 ----------------
__global__ void cast_w(const float* __restrict__ w, __bf16* __restrict__ o, int n4) {
  int idx = blockIdx.x * 256 + threadIdx.x;
  if (idx >= n4) return;
  floatx4 v = ((const floatx4*)w)[idx];
  bf16x4 pk;
  for (int e = 0; e < 4; ++e) pk[e] = (__bf16)v[e];
  ((bf16x4*)o)[idx] = pk;
}

// ---------------- normalize (optional) + transpose bf16 ----------------
__global__ void transpose_norm(const float* __restrict__ in, __bf16* __restrict__ out,
                               const float* __restrict__ mu, const float* __restrict__ rstd,
                               const float* __restrict__ gamma, const float* __restrict__ beta) {
  __shared__ float t[32][33];
  const int n = blockIdx.z;
  const int c0 = blockIdx.y * 32, s0 = blockIdx.x * 32;
  const float muv = mu ? mu[n] : 0.f;
  const float rs = rstd ? rstd[n] : 1.f;
  const float* inp = in + (size_t)n * CC * SS;
  for (int i = 0; i < 4; ++i) {
    int c = c0 + threadIdx.y + i * 8;
    float x = inp[(size_t)c * SS + s0 + threadIdx.x];
    if (gamma) x = (x - muv) * rs * gamma[c] + beta[c];
    t[threadIdx.y + i * 8][threadIdx.x] = x;
  }
  __syncthreads();
  __bf16* op = out + (size_t)n * SS * CC;
  for (int i = 0; i < 4; ++i) {
    int s = s0 + threadIdx.y + i * 8;
    op[(size_t)s * CC + c0 + threadIdx.x] = (__bf16)t[threadIdx.x][threadIdx.y + i * 8];
  }
}

// ---------------- GEMM mainloop: C(128x128) = A(MxK,row,lda) * Bt(NxK,row,ldb)^T ----------------
template <int KT>
__device__ __forceinline__ void gemm_tile(const __bf16* __restrict__ A,
                                          const __bf16* __restrict__ Bt, int lda, int ldb,
                                          int m0, int n0, __bf16* ldsA, __bf16* ldsB,
                                          floatx4 acc[4][4]) {
  const int tid = threadIdx.x;
  const int wave = tid >> 6, lane = tid & 63;
  const int colv = lane & 15, g = lane >> 4;
  const int wm = wave & 1, wn = wave >> 1;
  const int lrow = lane >> 3, lch = lane & 7;

#pragma unroll
  for (int mt = 0; mt < 4; ++mt)
#pragma unroll
    for (int nt = 0; nt < 4; ++nt) acc[mt][nt] = (floatx4)0.f;

  for (int k0 = 0; k0 < KT; k0 += 64) {
    __syncthreads();
#pragma unroll
    for (int j = 0; j < 4; ++j) {
      int r = wave * 32 + j * 8 + lrow;
      int ch = lch ^ (r & 7);
      async16(A + (size_t)(m0 + r) * lda + k0 + ch * 8, &ldsA[(wave * 32 + j * 8) * 64]);
      async16(Bt + (size_t)(n0 + r) * ldb + k0 + ch * 8, &ldsB[(wave * 32 + j * 8) * 64]);
    }
    __syncthreads();
#pragma unroll
    for (int c = 0; c < 2; ++c) {
      bf16x8 af[4], bf[4];
#pragma unroll
      for (int t = 0; t < 4; ++t) {
        int r = wm * 64 + t * 16 + colv;
        af[t] = *(const bf16x8*)&ldsA[r * 64 + (((c * 4 + g) ^ (r & 7)) << 3)];
        int rb = wn * 64 + t * 16 + colv;
        bf[t] = *(const bf16x8*)&ldsB[rb * 64 + (((c * 4 + g) ^ (rb & 7)) << 3)];
      }
#pragma unroll
      for (int mt = 0; mt < 4; ++mt)
#pragma unroll
        for (int nt = 0; nt < 4; ++nt)
          acc[mt][nt] = __builtin_amdgcn_mfma_f32_16x16x32_bf16(af[mt], bf[nt], acc[mt][nt], 0, 0, 0);
    }
  }
}

// Coalesced epilogue: stage C (+bias, cast bf16) into LDS as [n_local][m_local],
// then write rows of the M-contiguous output  dst[(n0+nl)*ldd + m0+ml].
__device__ __forceinline__ void epilogue_store_T(floatx4 acc[4][4], const float* __restrict__ bias,
                                                 int m0, int n0, __bf16* lds, __bf16* dst,
                                                 int ldd) {
  const int tid = threadIdx.x;
  const int wave = tid >> 6, lane = tid & 63;
  const int colv = lane & 15, g = lane >> 4;
  const int wm = wave & 1, wn = wave >> 1;
  __syncthreads();  // mainloop LDS reads done
#pragma unroll
  for (int mt = 0; mt < 4; ++mt) {
    int o = m0 + wm * 64 + mt * 16 + g * 4;
    floatx4 bv = *(const floatx4*)&bias[o];
#pragma unroll
    for (int nt = 0; nt < 4; ++nt) {
      int nl = wn * 64 + nt * 16 + colv;
      int ml = wm * 64 + mt * 16 + g * 4;
#pragma unroll
      for (int i = 0; i < 4; ++i)
        lds[nl * 128 + ml + i] = (__bf16)(acc[mt][nt][i] + bv[i]);
    }
  }
  __syncthreads();
#pragma unroll
  for (int p = 0; p < 8; ++p) {
    int nl = p * 16 + (tid >> 4);
    bf16x8 v = *(const bf16x8*)&lds[nl * 128 + (tid & 15) * 8];
    *(bf16x8*)&dst[(size_t)(n0 + nl) * ldd + m0 + (tid & 15) * 8] = v;
  }
}

// ---------------- GEMM 1: qT[n](2048x4096) = (Wq*xn)^T + bq ----------------
__global__ void __launch_bounds__(256) gemm_q(const __bf16* __restrict__ Wq,
                                              const __bf16* __restrict__ xnT,
                                              const float* __restrict__ bq,
                                              __bf16* __restrict__ qT) {
  __shared__ __bf16 lA[128 * 64], lB[128 * 64];
  const int n = blockIdx.z;
  const int m0 = blockIdx.x * 128, n0 = blockIdx.y * 128;
  floatx4 acc[4][4];
  gemm_tile<512>(Wq, xnT + (size_t)n * SS * CC, 512, 512, m0, n0, lA, lB, acc);
  epilogue_store_T(acc, bq, m0, n0, lA, qT + (size_t)n * SS * 4096, 4096);
}

// ---------------- GEMM 2: kv; K-half -> kT, V-half -> v (d-major) ----------------
__global__ void __launch_bounds__(256) gemm_kv(const __bf16* __restrict__ Wkv,
                                               const __bf16* __restrict__ ctxT,
                                               const float* __restrict__ bkv,
                                               __bf16* __restrict__ kT,
                                               __bf16* __restrict__ vv) {
  __shared__ __bf16 lA[128 * 64], lB[128 * 64];
  const int n = blockIdx.z;
  const int m0 = blockIdx.x * 128, n0 = blockIdx.y * 128;
  floatx4 acc[4][4];
  gemm_tile<512>(Wkv, ctxT + (size_t)n * SS * CC, 512, 512, m0, n0, lA, lB, acc);
  const int lane = threadIdx.x & 63, wave = threadIdx.x >> 6;
  const int colv = lane & 15, g = lane >> 4;
  const int wm = wave & 1, wn = wave >> 1;
  if (m0 < 4096) {
    epilogue_store_T(acc, bkv, m0, n0, lA, kT + (size_t)n * SS * 4096, 4096);
  } else {
    __bf16* vn = vv + (size_t)n * 4096 * SS;
#pragma unroll
    for (int mt = 0; mt < 4; ++mt) {
      int o = m0 + wm * 64 + mt * 16 + g * 4;
      floatx4 bias = *(const floatx4*)&bkv[o];
#pragma unroll
      for (int nt = 0; nt < 4; ++nt) {
        int s = n0 + wn * 64 + nt * 16 + colv;
#pragma unroll
        for (int i = 0; i < 4; ++i)
          vn[(size_t)(o + i - 4096) * SS + s] = (__bf16)(acc[mt][nt][i] + bias[i]);
      }
    }
  }
}

// ---------------- flash attention (PV d-split across waves) ----------------
// grid (S/64, H, nb); block 256 = 4 waves. Scores/softmax: wave w owns queries
// [qt*64 + w*16, +16). PV: wave w computes ALL 64 queries over d-slice w*128.
// LDS ~75 KB -> 2 blocks/CU. No min-waves bound: ~220 VGPR live, must not spill.
__global__ void __launch_bounds__(256) flash_attn(const __bf16* __restrict__ qT,
                                                  const __bf16* __restrict__ kT,
                                                  const __bf16* __restrict__ vv,
                                                  __bf16* __restrict__ yT) {
  const int n = blockIdx.z, h = blockIdx.y, qt = blockIdx.x;
  const int tid = threadIdx.x;
  const int wave = tid >> 6, lane = tid & 63;
  const int colv = lane & 15, g = lane >> 4;

  const __bf16* qTn = qT + (size_t)n * SS * 4096;
  const __bf16* kTn = kT + (size_t)n * SS * 4096;
  const __bf16* vn  = vv + (size_t)n * 4096 * SS;
  __bf16* yTn = yT + (size_t)n * SS * 4096;

  const int qrow0 = qt * 64 + wave * 16;  // owned for scores/softmax

  __shared__ __bf16 kbuf[32 * 512];     // row = key, xor-swizzled chunks
  __shared__ __bf16 vbuf[512 * 32];     // row = d
  __shared__ __bf16 pbuf[4 * 16 * 88];  // P staging, per-wave region, stride 88
  __shared__ float axs[64];             // per-query alpha (per kt)
  __shared__ float ils[64];             // per-query 1/l (epilogue)

  bf16x8 qf[16];
  {
    const __bf16* qp = qTn + (size_t)(qrow0 + colv) * 4096 + h * 512 + g * 8;
#pragma unroll
    for (int kc = 0; kc < 16; ++kc) qf[kc] = *(const bf16x8*)(qp + kc * 32);
  }

  // Oacc[qt4*8+dt]: rows qt4*16.., cols wave*128 + dt*16..
  floatx4 Oacc[32];
#pragma unroll
  for (int t = 0; t < 32; ++t) Oacc[t] = (floatx4)0.f;
  float mrun[4] = {-1e30f, -1e30f, -1e30f, -1e30f};
  float lrun[4] = {0.f, 0.f, 0.f, 0.f};

  __bf16* pb = pbuf + wave * (16 * 88);

  for (int kt = 0; kt < 64; ++kt) {
    const int key0 = kt * 32;
    __syncthreads();  // (a) prior tile's kbuf/vbuf/pbuf reads done
#pragma unroll
    for (int j = 0; j < 8; ++j) {
      int row = wave * 8 + j;
      const __bf16* src = kTn + (size_t)(key0 + row) * 4096 + h * 512 + ((lane ^ (row & 7)) << 3);
      async16(src, &kbuf[row * 512]);
    }
#pragma unroll
    for (int j = 0; j < 8; ++j) {
      int i = wave * 8 + j;
      int row = i * 16 + (lane >> 2);
      int ch = (lane & 3) ^ (row & 3);
      const __bf16* src = vn + (size_t)(h * 512 + row) * SS + key0 + ch * 8;
      async16(src, &vbuf[i * 16 * 32]);
    }
    __syncthreads();  // (b) staging complete

    floatx4 sc[2];
    sc[0] = (floatx4)0.f;
    sc[1] = (floatx4)0.f;
#pragma unroll
    for (int ct = 0; ct < 2; ++ct) {
      int key = ct * 16 + colv;
      const __bf16* kb = &kbuf[key * 512];
      int sw = key & 7;
#pragma unroll
      for (int kc = 0; kc < 16; ++kc) {
        bf16x8 bfr = *(const bf16x8*)(kb + (((kc * 4 + g) ^ sw) << 3));
        sc[ct] = __builtin_amdgcn_mfma_f32_16x16x32_bf16(qf[kc], bfr, sc[ct], 0, 0, 0);
      }
    }

    float p[2][4], alpha[4];
#pragma unroll
    for (int i = 0; i < 4; ++i) {
      float mx = fmaxf(sc[0][i], sc[1][i]);
#pragma unroll
      for (int off = 8; off >= 1; off >>= 1) mx = fmaxf(mx, __shfl_xor(mx, off, 64));
      float mnew = fmaxf(mrun[i], mx * QK_SCALE);
      alpha[i] = __expf(mrun[i] - mnew);
      float rs = 0.f;
#pragma unroll
      for (int ct = 0; ct < 2; ++ct) {
        float pvv = __expf(sc[ct][i] * QK_SCALE - mnew);
        p[ct][i] = pvv;
        rs += pvv;
      }
#pragma unroll
      for (int off = 8; off >= 1; off >>= 1) rs += __shfl_xor(rs, off, 64);
      lrun[i] = lrun[i] * alpha[i] + rs;
      mrun[i] = mnew;
    }
#pragma unroll
    for (int ct = 0; ct < 2; ++ct)
#pragma unroll
      for (int i = 0; i < 4; ++i)
        pb[(g * 4 + i) * 88 + ct * 16 + colv] = (__bf16)p[ct][i];
    if (colv == 0) {
      floatx4 av;
#pragma unroll
      for (int i = 0; i < 4; ++i) av[i] = alpha[i];
      *(floatx4*)&axs[wave * 16 + g * 4] = av;
    }
    __syncthreads();  // (d) P + alpha visible to all waves

    // rescale O (rows qt4-tile scaled by owning wave's alpha)
#pragma unroll
    for (int qt4 = 0; qt4 < 4; ++qt4) {
      floatx4 av = *(const floatx4*)&axs[qt4 * 16 + g * 4];
#pragma unroll
      for (int dt = 0; dt < 8; ++dt) {
        floatx4 o = Oacc[qt4 * 8 + dt];
#pragma unroll
        for (int i = 0; i < 4; ++i) o[i] *= av[i];
        Oacc[qt4 * 8 + dt] = o;
      }
    }
    // PV: A = P (4 query tiles), B = V slice d in [wave*128, +128)
    bf16x8 pa[4];
#pragma unroll
    for (int qt4 = 0; qt4 < 4; ++qt4)
      pa[qt4] = *(const bf16x8*)&pbuf[qt4 * (16 * 88) + colv * 88 + g * 8];
#pragma unroll
    for (int dt = 0; dt < 8; ++dt) {
      int drow = wave * 128 + dt * 16 + colv;
      bf16x8 vb = *(const bf16x8*)&vbuf[drow * 32 + ((g ^ (drow & 3)) << 3)];
#pragma unroll
      for (int qt4 = 0; qt4 < 4; ++qt4)
        Oacc[qt4 * 8 + dt] = __builtin_amdgcn_mfma_f32_16x16x32_bf16(pa[qt4], vb,
                                                                    Oacc[qt4 * 8 + dt], 0, 0, 0);
    }
  }

  if (colv == 0) {
    floatx4 lv;
#pragma unroll
    for (int i = 0; i < 4; ++i) lv[i] = 1.f / lrun[i];
    *(floatx4*)&ils[wave * 16 + g * 4] = lv;  // fresh array: no race with axs readers
  }
  __syncthreads();
#pragma unroll
  for (int qt4 = 0; qt4 < 4; ++qt4) {
    floatx4 lv = *(const floatx4*)&ils[qt4 * 16 + g * 4];
#pragma unroll
    for (int dt = 0; dt < 8; ++dt)
#pragma unroll
      for (int i = 0; i < 4; ++i) {
        size_t idx = (size_t)(qt * 64 + qt4 * 16 + g * 4 + i) * 4096 + h * 512 + wave * 128 +
                     dt * 16 + colv;
        yTn[idx] = (__bf16)(Oacc[qt4 * 8 + dt][i] * lv[i]);
      }
  }
}

// ---------------- GEMM 3 split-K=2: part[n][kz][c][s] = (Wo*y)_partial ----------------
// A = yT (M=2048=s, K=4096), Bt = Wo (N=512=c, K=4096); z = n*2+kz.
__global__ void __launch_bounds__(256) gemm_out_part(const __bf16* __restrict__ yT,
                                                     const __bf16* __restrict__ Wo,
                                                     float* __restrict__ part) {
  __shared__ __bf16 lA[128 * 64], lB[128 * 64];
  const int n = blockIdx.z >> 1, kz = blockIdx.z & 1;
  const int m0 = blockIdx.x * 128, n0 = blockIdx.y * 128;
  floatx4 acc[4][4];
  gemm_tile<2048>(yT + (size_t)n * SS * 4096 + kz * 2048, Wo + kz * 2048, 4096, 4096, m0, n0,
                  lA, lB, acc);
  const int lane = threadIdx.x & 63, wave = threadIdx.x >> 6;
  const int colv = lane & 15, g = lane >> 4;
  const int wm = wave & 1, wn = wave >> 1;
  float* pd = part + (size_t)(n * 2 + kz) * CC * SS;
#pragma unroll
  for (int mt = 0; mt < 4; ++mt) {
    int srow = m0 + wm * 64 + mt * 16 + g * 4;
#pragma unroll
    for (int nt = 0; nt < 4; ++nt) {
      int ccol = n0 + wn * 64 + nt * 16 + colv;
      *(floatx4*)&pd[(size_t)ccol * SS + srow] = acc[mt][nt];
    }
  }
}

// ---------------- combine: out = input + bo + p0 + p1 (per batch row in y) ----------------
__global__ void combine_out(const float* __restrict__ input, const float* __restrict__ bo,
                            const float* __restrict__ part, float* __restrict__ out) {
  const int n = blockIdx.y;
  size_t e = ((size_t)blockIdx.x * 256 + threadIdx.x) * 4;  // within-batch element
  int c = (int)(e >> 11);
  const float* p0 = part + (size_t)n * 2 * CC * SS + e;
  const float* p1 = p0 + (size_t)CC * SS;
  floatx4 a = *(const floatx4*)&input[(size_t)n * CC * SS + e];
  floatx4 v0 = *(const floatx4*)p0;
  floatx4 v1 = *(const floatx4*)p1;
  float b = bo[c];
  floatx4 o;
#pragma unroll
  for (int i = 0; i < 4; ++i) o[i] = a[i] + b + v0[i] + v1[i];
  *(floatx4*)&out[(size_t)n * CC * SS + e] = o;
}

// ---------------- host launcher ----------------
extern "C" void kernel_launch(void* const* d_in, const int* in_sizes, int n_in,
                              void* d_out, int out_size, void* d_ws, size_t ws_size,
                              hipStream_t stream) {
  const float* input   = (const float*)d_in[0];
  const float* context = (const float*)d_in[1];
  const float* gamma   = (const float*)d_in[2];
  const float* beta    = (const float*)d_in[3];
  const float* Wq      = (const float*)d_in[4];
  const float* bq      = (const float*)d_in[5];
  const float* Wkv     = (const float*)d_in[6];
  const float* bkv     = (const float*)d_in[7];
  const float* Wo      = (const float*)d_in[8];
  const float* bo      = (const float*)d_in[9];
  float* out = (float*)d_out;
  (void)in_sizes; (void)n_in; (void)out_size;

  char* ws = (char*)d_ws;
  size_t off = 0;
  auto alloc = [&](size_t b) {
    void* p = ws + off;
    off = (off + b + 255) & ~(size_t)255;
    return p;
  };
  float*  lnp  = (float*)alloc((size_t)4 * 128 * 2 * sizeof(float));
  float*  muA  = (float*)alloc(4 * sizeof(float));
  float*  rsA  = (float*)alloc(4 * sizeof(float));
  __bf16* WqB  = (__bf16*)alloc((size_t)4096 * 512 * 2);
  __bf16* WkvB = (__bf16*)alloc((size_t)8192 * 512 * 2);
  __bf16* WoB  = (__bf16*)alloc((size_t)512 * 4096 * 2);
  __bf16* xnT  = (__bf16*)alloc((size_t)NB * SS * CC * 2);
  __bf16* ctxT = (__bf16*)alloc((size_t)NB * SS * CC * 2);

  const size_t PB = (size_t)SS * 4096 * 2;  // 16 MB per batch of q/k/v/y

  ln_partial<<<dim3(512), dim3(256), 0, stream>>>(input, lnp);
  ln_final<<<dim3(4), dim3(128), 0, stream>>>(lnp, muA, rsA);
  cast_w<<<dim3(2048), dim3(256), 0, stream>>>(Wq, WqB, 524288);
  cast_w<<<dim3(4096), dim3(256), 0, stream>>>(Wkv, WkvB, 1048576);
  cast_w<<<dim3(2048), dim3(256), 0, stream>>>(Wo, WoB, 524288);
  transpose_norm<<<dim3(64, 16, 4), dim3(32, 8), 0, stream>>>(input, xnT, muA, rsA, gamma, beta);
  transpose_norm<<<dim3(64, 16, 4), dim3(32, 8), 0, stream>>>(context, ctxT, nullptr, nullptr,
                                                              nullptr, nullptr);

  const size_t MiB = 1ull << 20;
  if (ws_size >= off + 16 * PB + 8 * MiB) {
    // Path A: full-batch buffers; partials reuse qTb (33.6 MB <= 64 MB, dead post-flash)
    __bf16* qTb = (__bf16*)alloc(NB * PB);
    __bf16* kTb = (__bf16*)alloc(NB * PB);
    __bf16* vB  = (__bf16*)alloc(NB * PB);
    __bf16* yTb = (__bf16*)alloc(NB * PB);
    gemm_q<<<dim3(32, 16, 4), dim3(256), 0, stream>>>(WqB, xnT, bq, qTb);
    gemm_kv<<<dim3(64, 16, 4), dim3(256), 0, stream>>>(WkvB, ctxT, bkv, kTb, vB);
    flash_attn<<<dim3(32, 8, 4), dim3(256), 0, stream>>>(qTb, kTb, vB, yTb);
    float* part = (float*)qTb;
    gemm_out_part<<<dim3(16, 4, 8), dim3(256), 0, stream>>>(yTb, WoB, part);
    combine_out<<<dim3(1024, 4), dim3(256), 0, stream>>>(input, bo, part, out);
  } else if (ws_size >= off + 7 * PB + 8 * MiB) {
    // Path B: per-batch q/k/v, full yT; partials span qTb..vB (33.6 <= 48 MB, dead post-loop)
    __bf16* qTb = (__bf16*)alloc(PB);
    __bf16* kTb = (__bf16*)alloc(PB);
    __bf16* vB  = (__bf16*)alloc(PB);
    __bf16* yTb = (__bf16*)alloc(NB * PB);
    (void)kTb; (void)vB;
    for (int n = 0; n < NB; ++n) {
      gemm_q<<<dim3(32, 16, 1), dim3(256), 0, stream>>>(WqB, xnT + (size_t)n * SS * CC, bq, qTb);
      gemm_kv<<<dim3(64, 16, 1), dim3(256), 0, stream>>>(WkvB, ctxT + (size_t)n * SS * CC, bkv,
                                                         kTb, vB);
      flash_attn<<<dim3(32, 8, 1), dim3(256), 0, stream>>>(qTb, kTb, vB,
                                                           yTb + (size_t)n * SS * 4096);
    }
    float* part = (float*)qTb;
    gemm_out_part<<<dim3(16, 4, 8), dim3(256), 0, stream>>>(yTb, WoB, part);
    combine_out<<<dim3(1024, 4), dim3(256), 0, stream>>>(input, bo, part, out);
  } else {
    // Path C: everything per-batch; partials reuse qTb (8.4 <= 16 MB)
    __bf16* qTb = (__bf16*)alloc(PB);
    __bf16* kTb = (__bf16*)alloc(PB);
    __bf16* vB  = (__bf16*)alloc(PB);
    __bf16* yTb = (__bf16*)alloc(PB);
    for (int n = 0; n < NB; ++n) {
      gemm_q<<<dim3(32, 16, 1), dim3(256), 0, stream>>>(WqB, xnT + (size_t)n * SS * CC, bq, qTb);
      gemm_kv<<<dim3(64, 16, 1), dim3(256), 0, stream>>>(WkvB, ctxT + (size_t)n * SS * CC, bkv,
                                                         kTb, vB);
      flash_attn<<<dim3(32, 8, 1), dim3(256), 0, stream>>>(qTb, kTb, vB, yTb);
      float* part = (float*)qTb;
      gemm_out_part<<<dim3(16, 4, 2), dim3(256), 0, stream>>>(yTb, WoB, part);
      combine_out<<<dim3(1024, 1), dim3(256), 0, stream>>>(input + (size_t)n * CC * SS, bo, part,
                                                           out + (size_t)n * CC * SS);
    }
  }
}

// Round 5
// 1069.956 us; speedup vs baseline: 2.0882x; 1.1824x over previous
//
#include <hip/hip_runtime.h>
#include <cstdint>
#include <cstddef>

// CrossAttention1d: N=4, C=512, S=2048, CTX=512, S2=2048, H=8
// R5: flash softmax reductions moved from LDS-shuffles to DPP (VALU pipe);
// K/V staging reordered to hide load latency behind compute; QKV GEMMs fused
// into one dispatch; split-K=4 out GEMM; cast/transpose launch fusion.

#define NB 4
#define CC 512
#define SS 2048
#define HH 8
#define QK_SCALE 0.044194173824159216f  // 512^-0.5

typedef float  floatx4 __attribute__((ext_vector_type(4)));
typedef __bf16 bf16x8  __attribute__((ext_vector_type(8)));
typedef __bf16 bf16x4  __attribute__((ext_vector_type(4)));

__device__ __forceinline__ void async16(const void* g, void* l) {
  __builtin_amdgcn_global_load_lds((const __attribute__((address_space(1))) void*)g,
                                   (__attribute__((address_space(3))) void*)l, 16, 0, 0);
}

// DPP 16-lane row reductions (VALU pipe, not LDS). row_ror:n ctrl = 0x120+n.
template <int N>
__device__ __forceinline__ float dpp_ror_f(float v) {
  return __builtin_bit_cast(
      float, __builtin_amdgcn_update_dpp(0, __builtin_bit_cast(int, v), 0x120 + N, 0xf, 0xf, true));
}
__device__ __forceinline__ float red_max16(float v) {
  v = fmaxf(v, dpp_ror_f<8>(v));
  v = fmaxf(v, dpp_ror_f<4>(v));
  v = fmaxf(v, dpp_ror_f<2>(v));
  v = fmaxf(v, dpp_ror_f<1>(v));
  return v;
}
__device__ __forceinline__ float red_sum16(float v) {
  v += dpp_ror_f<8>(v);
  v += dpp_ror_f<4>(v);
  v += dpp_ror_f<2>(v);
  v += dpp_ror_f<1>(v);
  return v;
}

// ---------------- LayerNorm stats ----------------
__global__ void ln_partial(const float* __restrict__ x, float* __restrict__ part) {
  const int n = blockIdx.x >> 7, cidx = blockIdx.x & 127;
  const float* p = x + (size_t)n * (CC * SS) + (size_t)cidx * 8192;
  float s = 0.f, q = 0.f;
  for (int j = 0; j < 8; ++j) {
    floatx4 v = *(const floatx4*)&p[(j * 256 + threadIdx.x) * 4];
    for (int e = 0; e < 4; ++e) { s += v[e]; q += v[e] * v[e]; }
  }
  for (int off = 32; off >= 1; off >>= 1) {
    s += __shfl_down(s, off, 64);
    q += __shfl_down(q, off, 64);
  }
  __shared__ float shS[4], shQ[4];
  const int wave = threadIdx.x >> 6, lane = threadIdx.x & 63;
  if (lane == 0) { shS[wave] = s; shQ[wave] = q; }
  __syncthreads();
  if (threadIdx.x == 0) {
    part[blockIdx.x * 2] = shS[0] + shS[1] + shS[2] + shS[3];
    part[blockIdx.x * 2 + 1] = shQ[0] + shQ[1] + shQ[2] + shQ[3];
  }
}

__global__ void ln_final(const float* __restrict__ part, float* __restrict__ muA,
                         float* __restrict__ rsA) {
  const int n = blockIdx.x, tid = threadIdx.x;
  float s = part[(n * 128 + tid) * 2];
  float q = part[(n * 128 + tid) * 2 + 1];
  for (int off = 32; off >= 1; off >>= 1) {
    s += __shfl_down(s, off, 64);
    q += __shfl_down(q, off, 64);
  }
  __shared__ float shS[2], shQ[2];
  const int wave = tid >> 6, lane = tid & 63;
  if (lane == 0) { shS[wave] = s; shQ[wave] = q; }
  __syncthreads();
  if (tid == 0) {
    float S = shS[0] + shS[1], Q = shQ[0] + shQ[1];
    const float inv = 1.f / (float)(CC * SS);
    float m = S * inv;
    float v = Q * inv - m * m;
    muA[n] = m;
    rsA[n] = rsqrtf(v + 1e-5f);
  }
}

// ---------------- fused weight cast fp32 -> bf16 (3 tensors) ----------------
__global__ void cast_w3(const float* __restrict__ s0, __bf16* __restrict__ d0, int c0,
                        const float* __restrict__ s1, __bf16* __restrict__ d1, int c1,
                        const float* __restrict__ s2, __bf16* __restrict__ d2, int c2) {
  const int y = blockIdx.y;
  const float* s = y == 0 ? s0 : (y == 1 ? s1 : s2);
  __bf16* d = y == 0 ? d0 : (y == 1 ? d1 : d2);
  const int cnt = y == 0 ? c0 : (y == 1 ? c1 : c2);
  int idx = blockIdx.x * 256 + threadIdx.x;
  if (idx >= cnt) return;
  floatx4 v = ((const floatx4*)s)[idx];
  bf16x4 pk;
  for (int e = 0; e < 4; ++e) pk[e] = (__bf16)v[e];
  ((bf16x4*)d)[idx] = pk;
}

// ---------------- fused normalize+transpose (input) / transpose (context) ----------------
// z = n*2 + which; which==0: input w/ LN affine -> xnT; which==1: context -> ctxT
__global__ void transpose_nc(const float* __restrict__ input, const float* __restrict__ context,
                             __bf16* __restrict__ xnT, __bf16* __restrict__ ctxT,
                             const float* __restrict__ mu, const float* __restrict__ rstd,
                             const float* __restrict__ gamma, const float* __restrict__ beta) {
  __shared__ float t[32][33];
  const int n = blockIdx.z >> 1, which = blockIdx.z & 1;
  const int c0 = blockIdx.y * 32, s0 = blockIdx.x * 32;
  const float* inp = (which ? context : input) + (size_t)n * CC * SS;
  __bf16* op = (which ? ctxT : xnT) + (size_t)n * SS * CC;
  const float muv = which ? 0.f : mu[n];
  const float rs = which ? 1.f : rstd[n];
  for (int i = 0; i < 4; ++i) {
    int c = c0 + threadIdx.y + i * 8;
    float x = inp[(size_t)c * SS + s0 + threadIdx.x];
    if (!which) x = (x - muv) * rs * gamma[c] + beta[c];
    t[threadIdx.y + i * 8][threadIdx.x] = x;
  }
  __syncthreads();
  for (int i = 0; i < 4; ++i) {
    int s = s0 + threadIdx.y + i * 8;
    op[(size_t)s * CC + c0 + threadIdx.x] = (__bf16)t[threadIdx.x][threadIdx.y + i * 8];
  }
}

// ---------------- GEMM mainloop: C(128x128) = A(MxK,row,lda) * Bt(NxK,row,ldb)^T ----------------
template <int KT>
__device__ __forceinline__ void gemm_tile(const __bf16* __restrict__ A,
                                          const __bf16* __restrict__ Bt, int lda, int ldb,
                                          int m0, int n0, __bf16* ldsA, __bf16* ldsB,
                                          floatx4 acc[4][4]) {
  const int tid = threadIdx.x;
  const int wave = tid >> 6, lane = tid & 63;
  const int colv = lane & 15, g = lane >> 4;
  const int wm = wave & 1, wn = wave >> 1;
  const int lrow = lane >> 3, lch = lane & 7;

#pragma unroll
  for (int mt = 0; mt < 4; ++mt)
#pragma unroll
    for (int nt = 0; nt < 4; ++nt) acc[mt][nt] = (floatx4)0.f;

  for (int k0 = 0; k0 < KT; k0 += 64) {
    __syncthreads();
#pragma unroll
    for (int j = 0; j < 4; ++j) {
      int r = wave * 32 + j * 8 + lrow;
      int ch = lch ^ (r & 7);
      async16(A + (size_t)(m0 + r) * lda + k0 + ch * 8, &ldsA[(wave * 32 + j * 8) * 64]);
      async16(Bt + (size_t)(n0 + r) * ldb + k0 + ch * 8, &ldsB[(wave * 32 + j * 8) * 64]);
    }
    __syncthreads();
#pragma unroll
    for (int c = 0; c < 2; ++c) {
      bf16x8 af[4], bf[4];
#pragma unroll
      for (int t = 0; t < 4; ++t) {
        int r = wm * 64 + t * 16 + colv;
        af[t] = *(const bf16x8*)&ldsA[r * 64 + (((c * 4 + g) ^ (r & 7)) << 3)];
        int rb = wn * 64 + t * 16 + colv;
        bf[t] = *(const bf16x8*)&ldsB[rb * 64 + (((c * 4 + g) ^ (rb & 7)) << 3)];
      }
#pragma unroll
      for (int mt = 0; mt < 4; ++mt)
#pragma unroll
        for (int nt = 0; nt < 4; ++nt)
          acc[mt][nt] = __builtin_amdgcn_mfma_f32_16x16x32_bf16(af[mt], bf[nt], acc[mt][nt], 0, 0, 0);
    }
  }
}

// Coalesced epilogue via LDS transpose: dst[(n0+nl)*ldd + m0+ml] (+bias, bf16)
__device__ __forceinline__ void epilogue_store_T(floatx4 acc[4][4], const float* __restrict__ bias,
                                                 int m0, int n0, __bf16* lds, __bf16* dst,
                                                 int ldd) {
  const int tid = threadIdx.x;
  const int wave = tid >> 6, lane = tid & 63;
  const int colv = lane & 15, g = lane >> 4;
  const int wm = wave & 1, wn = wave >> 1;
  __syncthreads();  // mainloop LDS reads done
#pragma unroll
  for (int mt = 0; mt < 4; ++mt) {
    int o = m0 + wm * 64 + mt * 16 + g * 4;
    floatx4 bv = *(const floatx4*)&bias[o];
#pragma unroll
    for (int nt = 0; nt < 4; ++nt) {
      int nl = wn * 64 + nt * 16 + colv;
      int ml = wm * 64 + mt * 16 + g * 4;
#pragma unroll
      for (int i = 0; i < 4; ++i)
        lds[nl * 128 + ml + i] = (__bf16)(acc[mt][nt][i] + bv[i]);
    }
  }
  __syncthreads();
#pragma unroll
  for (int p = 0; p < 8; ++p) {
    int nl = p * 16 + (tid >> 4);
    bf16x8 v = *(const bf16x8*)&lds[nl * 128 + (tid & 15) * 8];
    *(bf16x8*)&dst[(size_t)(n0 + nl) * ldd + m0 + (tid & 15) * 8] = v;
  }
}

// ---------------- fused QKV GEMM ----------------
// x<32: qT rows = Wq*xn; x in [32,64): kT rows = Wkv[0:4096]*ctx;
// x in [64,96): V rows (d-major) = Wkv[4096:8192]*ctx.
__global__ void __launch_bounds__(256) gemm_qkv(const __bf16* __restrict__ WqB,
                                                const __bf16* __restrict__ WkvB,
                                                const __bf16* __restrict__ xnT,
                                                const __bf16* __restrict__ ctxT,
                                                const float* __restrict__ bq,
                                                const float* __restrict__ bkv,
                                                __bf16* __restrict__ qT,
                                                __bf16* __restrict__ kT,
                                                __bf16* __restrict__ vv) {
  __shared__ __bf16 lA[128 * 64], lB[128 * 64];
  const int n = blockIdx.z, xb = blockIdx.x;
  const int n0 = blockIdx.y * 128;
  const bool isq = xb < 32;
  const int m0 = isq ? xb * 128 : (xb - 32) * 128;  // within Wq or Wkv
  const __bf16* A = isq ? WqB : WkvB;
  const __bf16* Bt = (isq ? xnT : ctxT) + (size_t)n * SS * CC;
  const float* bias = isq ? bq : bkv;
  floatx4 acc[4][4];
  gemm_tile<512>(A, Bt, 512, 512, m0, n0, lA, lB, acc);
  if (xb < 64) {
    __bf16* dst = (isq ? qT : kT) + (size_t)n * SS * 4096;
    epilogue_store_T(acc, bias, m0, n0, lA, dst, 4096);
  } else {
    const int lane = threadIdx.x & 63, wave = threadIdx.x >> 6;
    const int colv = lane & 15, g = lane >> 4;
    const int wm = wave & 1, wn = wave >> 1;
    __bf16* vn = vv + (size_t)n * 4096 * SS;
#pragma unroll
    for (int mt = 0; mt < 4; ++mt) {
      int o = m0 + wm * 64 + mt * 16 + g * 4;
      floatx4 bv = *(const floatx4*)&bias[o];
#pragma unroll
      for (int nt = 0; nt < 4; ++nt) {
        int s = n0 + wn * 64 + nt * 16 + colv;
#pragma unroll
        for (int i = 0; i < 4; ++i)
          vn[(size_t)(o + i - 4096) * SS + s] = (__bf16)(acc[mt][nt][i] + bv[i]);
      }
    }
  }
}

// ---------------- flash attention (PV d-split, DPP softmax, staged prefetch) ----------------
// grid (S/64, H, nb); block 256 = 4 waves; wave owns 16 queries for scores,
// all 64 queries over d-slice wave*128 for PV.
__global__ void __launch_bounds__(256) flash_attn(const __bf16* __restrict__ qT,
                                                  const __bf16* __restrict__ kT,
                                                  const __bf16* __restrict__ vv,
                                                  __bf16* __restrict__ yT) {
  const int n = blockIdx.z, h = blockIdx.y, qt = blockIdx.x;
  const int tid = threadIdx.x;
  const int wave = tid >> 6, lane = tid & 63;
  const int colv = lane & 15, g = lane >> 4;

  const __bf16* qTn = qT + (size_t)n * SS * 4096;
  const __bf16* kTn = kT + (size_t)n * SS * 4096;
  const __bf16* vn  = vv + (size_t)n * 4096 * SS;
  __bf16* yTn = yT + (size_t)n * SS * 4096;

  const int qrow0 = qt * 64 + wave * 16;

  __shared__ __bf16 kbuf[32 * 512];
  __shared__ __bf16 vbuf[512 * 32];
  __shared__ __bf16 pbuf[4 * 16 * 88];
  __shared__ float axs[64];
  __shared__ float ils[64];

  bf16x8 qf[16];
  {
    const __bf16* qp = qTn + (size_t)(qrow0 + colv) * 4096 + h * 512 + g * 8;
#pragma unroll
    for (int kc = 0; kc < 16; ++kc) qf[kc] = *(const bf16x8*)(qp + kc * 32);
  }

  floatx4 Oacc[32];
#pragma unroll
  for (int t = 0; t < 32; ++t) Oacc[t] = (floatx4)0.f;
  float mrun[4] = {-1e30f, -1e30f, -1e30f, -1e30f};
  float lrun[4] = {0.f, 0.f, 0.f, 0.f};

  __bf16* pb = pbuf + wave * (16 * 88);

  // staging helpers (wave-uniform base + lane*16 per async16)
  auto stageK = [&](int kt) {
    const int key0 = kt * 32;
#pragma unroll
    for (int j = 0; j < 8; ++j) {
      int row = wave * 8 + j;
      const __bf16* src = kTn + (size_t)(key0 + row) * 4096 + h * 512 + ((lane ^ (row & 7)) << 3);
      async16(src, &kbuf[row * 512]);
    }
  };
  auto stageV = [&](int kt) {
    const int key0 = kt * 32;
#pragma unroll
    for (int j = 0; j < 8; ++j) {
      int i = wave * 8 + j;
      int row = i * 16 + (lane >> 2);
      int ch = (lane & 3) ^ (row & 3);
      const __bf16* src = vn + (size_t)(h * 512 + row) * SS + key0 + ch * 8;
      async16(src, &vbuf[i * 16 * 32]);
    }
  };

  stageK(0);
  stageV(0);

  for (int kt = 0; kt < 64; ++kt) {
    __syncthreads();  // (b) staged K/V drained & visible

    floatx4 sc[2];
    sc[0] = (floatx4)0.f;
    sc[1] = (floatx4)0.f;
#pragma unroll
    for (int ct = 0; ct < 2; ++ct) {
      int key = ct * 16 + colv;
      const __bf16* kb = &kbuf[key * 512];
      int sw = key & 7;
#pragma unroll
      for (int kc = 0; kc < 16; ++kc) {
        bf16x8 bfr = *(const bf16x8*)(kb + (((kc * 4 + g) ^ sw) << 3));
        sc[ct] = __builtin_amdgcn_mfma_f32_16x16x32_bf16(qf[kc], bfr, sc[ct], 0, 0, 0);
      }
    }

    float p[2][4], alpha[4];
#pragma unroll
    for (int i = 0; i < 4; ++i) {
      float mx = red_max16(fmaxf(sc[0][i], sc[1][i]));
      float mnew = fmaxf(mrun[i], mx * QK_SCALE);
      alpha[i] = __expf(mrun[i] - mnew);
      float rs = 0.f;
#pragma unroll
      for (int ct = 0; ct < 2; ++ct) {
        float pvv = __expf(sc[ct][i] * QK_SCALE - mnew);
        p[ct][i] = pvv;
        rs += pvv;
      }
      rs = red_sum16(rs);
      lrun[i] = lrun[i] * alpha[i] + rs;
      mrun[i] = mnew;
    }
#pragma unroll
    for (int ct = 0; ct < 2; ++ct)
#pragma unroll
      for (int i = 0; i < 4; ++i)
        pb[(g * 4 + i) * 88 + ct * 16 + colv] = (__bf16)p[ct][i];
    if (colv == 0) {
      floatx4 av;
#pragma unroll
      for (int i = 0; i < 4; ++i) av[i] = alpha[i];
      *(floatx4*)&axs[wave * 16 + g * 4] = av;
    }
    __syncthreads();  // (d) P + alpha ready; all kbuf reads done

    if (kt < 63) stageK(kt + 1);  // kbuf free during PV phase

#pragma unroll
    for (int qt4 = 0; qt4 < 4; ++qt4) {
      floatx4 av = *(const floatx4*)&axs[qt4 * 16 + g * 4];
#pragma unroll
      for (int dt = 0; dt < 8; ++dt) {
        floatx4 o = Oacc[qt4 * 8 + dt];
#pragma unroll
        for (int i = 0; i < 4; ++i) o[i] *= av[i];
        Oacc[qt4 * 8 + dt] = o;
      }
    }
    bf16x8 pa[4];
#pragma unroll
    for (int qt4 = 0; qt4 < 4; ++qt4)
      pa[qt4] = *(const bf16x8*)&pbuf[qt4 * (16 * 88) + colv * 88 + g * 8];
#pragma unroll
    for (int dt = 0; dt < 8; ++dt) {
      int drow = wave * 128 + dt * 16 + colv;
      bf16x8 vb = *(const bf16x8*)&vbuf[drow * 32 + ((g ^ (drow & 3)) << 3)];
#pragma unroll
      for (int qt4 = 0; qt4 < 4; ++qt4)
        Oacc[qt4 * 8 + dt] = __builtin_amdgcn_mfma_f32_16x16x32_bf16(pa[qt4], vb,
                                                                    Oacc[qt4 * 8 + dt], 0, 0, 0);
    }
    __syncthreads();  // (a) PV reads done -> vbuf free
    if (kt < 63) stageV(kt + 1);
  }

  if (colv == 0) {
    floatx4 lv;
#pragma unroll
    for (int i = 0; i < 4; ++i) lv[i] = 1.f / lrun[i];
    *(floatx4*)&ils[wave * 16 + g * 4] = lv;
  }
  __syncthreads();
#pragma unroll
  for (int qt4 = 0; qt4 < 4; ++qt4) {
    floatx4 lv = *(const floatx4*)&ils[qt4 * 16 + g * 4];
#pragma unroll
    for (int dt = 0; dt < 8; ++dt)
#pragma unroll
      for (int i = 0; i < 4; ++i) {
        size_t idx = (size_t)(qt * 64 + qt4 * 16 + g * 4 + i) * 4096 + h * 512 + wave * 128 +
                     dt * 16 + colv;
        yTn[idx] = (__bf16)(Oacc[qt4 * 8 + dt][i] * lv[i]);
      }
  }
}

// ---------------- out GEMM, split-K into SPLITS partials ----------------
// A = yT (M=2048=s, K=4096), Bt = Wo (N=512=c); slab z = (n-nbase)*SPLITS+kz.
template <int SPLITS>
__global__ void __launch_bounds__(256) gemm_out_part(const __bf16* __restrict__ yT,
                                                     const __bf16* __restrict__ Wo,
                                                     float* __restrict__ part, int nbase) {
  constexpr int KT = 4096 / SPLITS;
  __shared__ __bf16 lA[128 * 64], lB[128 * 64];
  const int n = nbase + (int)(blockIdx.z / SPLITS), kz = (int)(blockIdx.z % SPLITS);
  const int m0 = blockIdx.x * 128, n0 = blockIdx.y * 128;
  floatx4 acc[4][4];
  gemm_tile<KT>(yT + (size_t)n * SS * 4096 + kz * KT, Wo + kz * KT, 4096, 4096, m0, n0, lA, lB,
                acc);
  const int lane = threadIdx.x & 63, wave = threadIdx.x >> 6;
  const int colv = lane & 15, g = lane >> 4;
  const int wm = wave & 1, wn = wave >> 1;
  float* pd = part + (size_t)blockIdx.z * CC * SS;
#pragma unroll
  for (int mt = 0; mt < 4; ++mt) {
    int srow = m0 + wm * 64 + mt * 16 + g * 4;
#pragma unroll
    for (int nt = 0; nt < 4; ++nt) {
      int ccol = n0 + wn * 64 + nt * 16 + colv;
      *(floatx4*)&pd[(size_t)ccol * SS + srow] = acc[mt][nt];
    }
  }
}

// ---------------- combine: out = input + bo + sum(partials) ----------------
__global__ void combine_out(const float* __restrict__ input, const float* __restrict__ bo,
                            const float* __restrict__ part, float* __restrict__ out, int parts) {
  const int n = blockIdx.y;
  size_t e = ((size_t)blockIdx.x * 256 + threadIdx.x) * 4;
  int c = (int)(e >> 11);
  floatx4 a = *(const floatx4*)&input[(size_t)n * CC * SS + e];
  float b = bo[c];
  floatx4 o;
#pragma unroll
  for (int i = 0; i < 4; ++i) o[i] = a[i] + b;
  for (int k = 0; k < parts; ++k) {
    floatx4 v = *(const floatx4*)&part[((size_t)n * parts + k) * CC * SS + e];
#pragma unroll
    for (int i = 0; i < 4; ++i) o[i] += v[i];
  }
  *(floatx4*)&out[(size_t)n * CC * SS + e] = o;
}

// ---------------- host launcher ----------------
extern "C" void kernel_launch(void* const* d_in, const int* in_sizes, int n_in,
                              void* d_out, int out_size, void* d_ws, size_t ws_size,
                              hipStream_t stream) {
  const float* input   = (const float*)d_in[0];
  const float* context = (const float*)d_in[1];
  const float* gamma   = (const float*)d_in[2];
  const float* beta    = (const float*)d_in[3];
  const float* Wq      = (const float*)d_in[4];
  const float* bq      = (const float*)d_in[5];
  const float* Wkv     = (const float*)d_in[6];
  const float* bkv     = (const float*)d_in[7];
  const float* Wo      = (const float*)d_in[8];
  const float* bo      = (const float*)d_in[9];
  float* out = (float*)d_out;
  (void)in_sizes; (void)n_in; (void)out_size;

  char* ws = (char*)d_ws;
  size_t off = 0;
  auto alloc = [&](size_t b) {
    void* p = ws + off;
    off = (off + b + 255) & ~(size_t)255;
    return p;
  };
  float*  lnp  = (float*)alloc((size_t)4 * 128 * 2 * sizeof(float));
  float*  muA  = (float*)alloc(4 * sizeof(float));
  float*  rsA  = (float*)alloc(4 * sizeof(float));
  __bf16* WqB  = (__bf16*)alloc((size_t)4096 * 512 * 2);
  __bf16* WkvB = (__bf16*)alloc((size_t)8192 * 512 * 2);
  __bf16* WoB  = (__bf16*)alloc((size_t)512 * 4096 * 2);
  __bf16* xnT  = (__bf16*)alloc((size_t)NB * SS * CC * 2);
  __bf16* ctxT = (__bf16*)alloc((size_t)NB * SS * CC * 2);

  const size_t PB = (size_t)SS * 4096 * 2;  // 16 MB per batch of q/k/v/y

  ln_partial<<<dim3(512), dim3(256), 0, stream>>>(input, lnp);
  ln_final<<<dim3(4), dim3(128), 0, stream>>>(lnp, muA, rsA);
  cast_w3<<<dim3(4096, 3), dim3(256), 0, stream>>>(Wq, WqB, 524288, Wkv, WkvB, 1048576, Wo, WoB,
                                                   524288);
  transpose_nc<<<dim3(64, 16, 8), dim3(32, 8), 0, stream>>>(input, context, xnT, ctxT, muA, rsA,
                                                            gamma, beta);

  const size_t MiB = 1ull << 20;
  if (ws_size >= off + 16 * PB + 8 * MiB) {
    // Path A: full-batch; split-K=4 partials (67 MB) reuse dead qTb+kTb (128 MB)
    __bf16* qTb = (__bf16*)alloc(NB * PB);
    __bf16* kTb = (__bf16*)alloc(NB * PB);
    __bf16* vB  = (__bf16*)alloc(NB * PB);
    __bf16* yTb = (__bf16*)alloc(NB * PB);
    gemm_qkv<<<dim3(96, 16, 4), dim3(256), 0, stream>>>(WqB, WkvB, xnT, ctxT, bq, bkv, qTb, kTb,
                                                        vB);
    flash_attn<<<dim3(32, 8, 4), dim3(256), 0, stream>>>(qTb, kTb, vB, yTb);
    float* part = (float*)qTb;
    gemm_out_part<4><<<dim3(16, 4, 16), dim3(256), 0, stream>>>(yTb, WoB, part, 0);
    combine_out<<<dim3(1024, 4), dim3(256), 0, stream>>>(input, bo, part, out, 4);
  } else if (ws_size >= off + 7 * PB + 8 * MiB) {
    // Path B: per-batch q/k/v, full yT; split-K=2 partials (33.6 MB) in qTb..vB (48 MB)
    __bf16* qTb = (__bf16*)alloc(PB);
    __bf16* kTb = (__bf16*)alloc(PB);
    __bf16* vB  = (__bf16*)alloc(PB);
    __bf16* yTb = (__bf16*)alloc(NB * PB);
    for (int n = 0; n < NB; ++n) {
      gemm_qkv<<<dim3(96, 16, 1), dim3(256), 0, stream>>>(WqB, WkvB, xnT + (size_t)n * SS * CC,
                                                          ctxT + (size_t)n * SS * CC, bq, bkv,
                                                          qTb, kTb, vB);
      flash_attn<<<dim3(32, 8, 1), dim3(256), 0, stream>>>(qTb, kTb, vB,
                                                           yTb + (size_t)n * SS * 4096);
    }
    float* part = (float*)qTb;
    gemm_out_part<2><<<dim3(16, 4, 8), dim3(256), 0, stream>>>(yTb, WoB, part, 0);
    combine_out<<<dim3(1024, 4), dim3(256), 0, stream>>>(input, bo, part, out, 2);
  } else {
    // Path C: everything per-batch; split-K=4 partials (16.8 MB) in qTb+kTb (32 MB)
    __bf16* qTb = (__bf16*)alloc(PB);
    __bf16* kTb = (__bf16*)alloc(PB);
    __bf16* vB  = (__bf16*)alloc(PB);
    __bf16* yTb = (__bf16*)alloc(PB);
    for (int n = 0; n < NB; ++n) {
      gemm_qkv<<<dim3(96, 16, 1), dim3(256), 0, stream>>>(WqB, WkvB, xnT + (size_t)n * SS * CC,
                                                          ctxT + (size_t)n * SS * CC, bq, bkv,
                                                          qTb, kTb, vB);
      flash_attn<<<dim3(32, 8, 1), dim3(256), 0, stream>>>(qTb, kTb, vB, yTb);
      float* part = (float*)qTb;
      gemm_out_part<4><<<dim3(16, 4, 4), dim3(256), 0, stream>>>(yTb, WoB, part, 0);
      combine_out<<<dim3(1024, 1), dim3(256), 0, stream>>>(input + (size_t)n * CC * SS, bo, part,
                                                           out + (size_t)n * CC * SS, 4);
    }
  }
}

// Round 6
// 1063.580 us; speedup vs baseline: 2.1007x; 1.0060x over previous
//
#include <hip/hip_runtime.h>
#include <cstdint>
#include <cstddef>

// CrossAttention1d: N=4, C=512, S=2048, CTX=512, S2=2048, H=8
// R6: fused single-pass out-GEMM (M=c,N=s -> native coalesced fp32 stores w/
// residual+bias epilogue; no split-K partials, no combine pass); cast fused
// into ln_partial dispatch. Flash (195us, LDS-BW-saturated) unchanged.

#define NB 4
#define CC 512
#define SS 2048
#define HH 8
#define QK_SCALE 0.044194173824159216f  // 512^-0.5

typedef float  floatx4 __attribute__((ext_vector_type(4)));
typedef __bf16 bf16x8  __attribute__((ext_vector_type(8)));
typedef __bf16 bf16x4  __attribute__((ext_vector_type(4)));

__device__ __forceinline__ void async16(const void* g, void* l) {
  __builtin_amdgcn_global_load_lds((const __attribute__((address_space(1))) void*)g,
                                   (__attribute__((address_space(3))) void*)l, 16, 0, 0);
}

// DPP 16-lane row reductions (VALU pipe, not LDS). row_ror:n ctrl = 0x120+n.
template <int N>
__device__ __forceinline__ float dpp_ror_f(float v) {
  return __builtin_bit_cast(
      float, __builtin_amdgcn_update_dpp(0, __builtin_bit_cast(int, v), 0x120 + N, 0xf, 0xf, true));
}
__device__ __forceinline__ float red_max16(float v) {
  v = fmaxf(v, dpp_ror_f<8>(v));
  v = fmaxf(v, dpp_ror_f<4>(v));
  v = fmaxf(v, dpp_ror_f<2>(v));
  v = fmaxf(v, dpp_ror_f<1>(v));
  return v;
}
__device__ __forceinline__ float red_sum16(float v) {
  v += dpp_ror_f<8>(v);
  v += dpp_ror_f<4>(v);
  v += dpp_ror_f<2>(v);
  v += dpp_ror_f<1>(v);
  return v;
}

// ---------------- fused: LN partial stats (blocks 0..511) + weight casts ----------------
__global__ void prep1(const float* __restrict__ x, float* __restrict__ part,
                      const float* __restrict__ Wq, __bf16* __restrict__ WqB,
                      const float* __restrict__ Wkv, __bf16* __restrict__ WkvB,
                      const float* __restrict__ Wo, __bf16* __restrict__ WoB) {
  const int bx = blockIdx.x;
  if (bx < 512) {
    const int n = bx >> 7, cidx = bx & 127;
    const float* p = x + (size_t)n * (CC * SS) + (size_t)cidx * 8192;
    float s = 0.f, q = 0.f;
    for (int j = 0; j < 8; ++j) {
      floatx4 v = *(const floatx4*)&p[(j * 256 + threadIdx.x) * 4];
      for (int e = 0; e < 4; ++e) { s += v[e]; q += v[e] * v[e]; }
    }
    for (int off = 32; off >= 1; off >>= 1) {
      s += __shfl_down(s, off, 64);
      q += __shfl_down(q, off, 64);
    }
    __shared__ float shS[4], shQ[4];
    const int wave = threadIdx.x >> 6, lane = threadIdx.x & 63;
    if (lane == 0) { shS[wave] = s; shQ[wave] = q; }
    __syncthreads();
    if (threadIdx.x == 0) {
      part[bx * 2] = shS[0] + shS[1] + shS[2] + shS[3];
      part[bx * 2 + 1] = shQ[0] + shQ[1] + shQ[2] + shQ[3];
    }
  } else {
    const int r = bx - 512;
    const int y = r >> 12, xb = r & 4095;
    const float* s = y == 0 ? Wq : (y == 1 ? Wkv : Wo);
    __bf16* d = y == 0 ? WqB : (y == 1 ? WkvB : WoB);
    const int cnt = y == 1 ? 1048576 : 524288;
    int idx = xb * 256 + threadIdx.x;
    if (idx >= cnt) return;
    floatx4 v = ((const floatx4*)s)[idx];
    bf16x4 pk;
    for (int e = 0; e < 4; ++e) pk[e] = (__bf16)v[e];
    ((bf16x4*)d)[idx] = pk;
  }
}

__global__ void ln_final(const float* __restrict__ part, float* __restrict__ muA,
                         float* __restrict__ rsA) {
  const int n = blockIdx.x, tid = threadIdx.x;
  float s = part[(n * 128 + tid) * 2];
  float q = part[(n * 128 + tid) * 2 + 1];
  for (int off = 32; off >= 1; off >>= 1) {
    s += __shfl_down(s, off, 64);
    q += __shfl_down(q, off, 64);
  }
  __shared__ float shS[2], shQ[2];
  const int wave = tid >> 6, lane = tid & 63;
  if (lane == 0) { shS[wave] = s; shQ[wave] = q; }
  __syncthreads();
  if (tid == 0) {
    float S = shS[0] + shS[1], Q = shQ[0] + shQ[1];
    const float inv = 1.f / (float)(CC * SS);
    float m = S * inv;
    float v = Q * inv - m * m;
    muA[n] = m;
    rsA[n] = rsqrtf(v + 1e-5f);
  }
}

// ---------------- fused normalize+transpose (input) / transpose (context) ----------------
__global__ void transpose_nc(const float* __restrict__ input, const float* __restrict__ context,
                             __bf16* __restrict__ xnT, __bf16* __restrict__ ctxT,
                             const float* __restrict__ mu, const float* __restrict__ rstd,
                             const float* __restrict__ gamma, const float* __restrict__ beta) {
  __shared__ float t[32][33];
  const int n = blockIdx.z >> 1, which = blockIdx.z & 1;
  const int c0 = blockIdx.y * 32, s0 = blockIdx.x * 32;
  const float* inp = (which ? context : input) + (size_t)n * CC * SS;
  __bf16* op = (which ? ctxT : xnT) + (size_t)n * SS * CC;
  const float muv = which ? 0.f : mu[n];
  const float rs = which ? 1.f : rstd[n];
  for (int i = 0; i < 4; ++i) {
    int c = c0 + threadIdx.y + i * 8;
    float x = inp[(size_t)c * SS + s0 + threadIdx.x];
    if (!which) x = (x - muv) * rs * gamma[c] + beta[c];
    t[threadIdx.y + i * 8][threadIdx.x] = x;
  }
  __syncthreads();
  for (int i = 0; i < 4; ++i) {
    int s = s0 + threadIdx.y + i * 8;
    op[(size_t)s * CC + c0 + threadIdx.x] = (__bf16)t[threadIdx.x][threadIdx.y + i * 8];
  }
}

// ---------------- GEMM mainloop: C(128x128) = A(MxK,row,lda) * Bt(NxK,row,ldb)^T ----------------
template <int KT>
__device__ __forceinline__ void gemm_tile(const __bf16* __restrict__ A,
                                          const __bf16* __restrict__ Bt, int lda, int ldb,
                                          int m0, int n0, __bf16* ldsA, __bf16* ldsB,
                                          floatx4 acc[4][4]) {
  const int tid = threadIdx.x;
  const int wave = tid >> 6, lane = tid & 63;
  const int colv = lane & 15, g = lane >> 4;
  const int wm = wave & 1, wn = wave >> 1;
  const int lrow = lane >> 3, lch = lane & 7;

#pragma unroll
  for (int mt = 0; mt < 4; ++mt)
#pragma unroll
    for (int nt = 0; nt < 4; ++nt) acc[mt][nt] = (floatx4)0.f;

  for (int k0 = 0; k0 < KT; k0 += 64) {
    __syncthreads();
#pragma unroll
    for (int j = 0; j < 4; ++j) {
      int r = wave * 32 + j * 8 + lrow;
      int ch = lch ^ (r & 7);
      async16(A + (size_t)(m0 + r) * lda + k0 + ch * 8, &ldsA[(wave * 32 + j * 8) * 64]);
      async16(Bt + (size_t)(n0 + r) * ldb + k0 + ch * 8, &ldsB[(wave * 32 + j * 8) * 64]);
    }
    __syncthreads();
#pragma unroll
    for (int c = 0; c < 2; ++c) {
      bf16x8 af[4], bf[4];
#pragma unroll
      for (int t = 0; t < 4; ++t) {
        int r = wm * 64 + t * 16 + colv;
        af[t] = *(const bf16x8*)&ldsA[r * 64 + (((c * 4 + g) ^ (r & 7)) << 3)];
        int rb = wn * 64 + t * 16 + colv;
        bf[t] = *(const bf16x8*)&ldsB[rb * 64 + (((c * 4 + g) ^ (rb & 7)) << 3)];
      }
#pragma unroll
      for (int mt = 0; mt < 4; ++mt)
#pragma unroll
        for (int nt = 0; nt < 4; ++nt)
          acc[mt][nt] = __builtin_amdgcn_mfma_f32_16x16x32_bf16(af[mt], bf[nt], acc[mt][nt], 0, 0, 0);
    }
  }
}

// Coalesced epilogue via LDS transpose: dst[(n0+nl)*ldd + m0+ml] (+bias, bf16)
__device__ __forceinline__ void epilogue_store_T(floatx4 acc[4][4], const float* __restrict__ bias,
                                                 int m0, int n0, __bf16* lds, __bf16* dst,
                                                 int ldd) {
  const int tid = threadIdx.x;
  const int wave = tid >> 6, lane = tid & 63;
  const int colv = lane & 15, g = lane >> 4;
  const int wm = wave & 1, wn = wave >> 1;
  __syncthreads();  // mainloop LDS reads done
#pragma unroll
  for (int mt = 0; mt < 4; ++mt) {
    int o = m0 + wm * 64 + mt * 16 + g * 4;
    floatx4 bv = *(const floatx4*)&bias[o];
#pragma unroll
    for (int nt = 0; nt < 4; ++nt) {
      int nl = wn * 64 + nt * 16 + colv;
      int ml = wm * 64 + mt * 16 + g * 4;
#pragma unroll
      for (int i = 0; i < 4; ++i)
        lds[nl * 128 + ml + i] = (__bf16)(acc[mt][nt][i] + bv[i]);
    }
  }
  __syncthreads();
#pragma unroll
  for (int p = 0; p < 8; ++p) {
    int nl = p * 16 + (tid >> 4);
    bf16x8 v = *(const bf16x8*)&lds[nl * 128 + (tid & 15) * 8];
    *(bf16x8*)&dst[(size_t)(n0 + nl) * ldd + m0 + (tid & 15) * 8] = v;
  }
}

// ---------------- fused QKV GEMM ----------------
__global__ void __launch_bounds__(256) gemm_qkv(const __bf16* __restrict__ WqB,
                                                const __bf16* __restrict__ WkvB,
                                                const __bf16* __restrict__ xnT,
                                                const __bf16* __restrict__ ctxT,
                                                const float* __restrict__ bq,
                                                const float* __restrict__ bkv,
                                                __bf16* __restrict__ qT,
                                                __bf16* __restrict__ kT,
                                                __bf16* __restrict__ vv) {
  __shared__ __bf16 lA[128 * 64], lB[128 * 64];
  const int n = blockIdx.z, xb = blockIdx.x;
  const int n0 = blockIdx.y * 128;
  const bool isq = xb < 32;
  const int m0 = isq ? xb * 128 : (xb - 32) * 128;
  const __bf16* A = isq ? WqB : WkvB;
  const __bf16* Bt = (isq ? xnT : ctxT) + (size_t)n * SS * CC;
  const float* bias = isq ? bq : bkv;
  floatx4 acc[4][4];
  gemm_tile<512>(A, Bt, 512, 512, m0, n0, lA, lB, acc);
  if (xb < 64) {
    __bf16* dst = (isq ? qT : kT) + (size_t)n * SS * 4096;
    epilogue_store_T(acc, bias, m0, n0, lA, dst, 4096);
  } else {
    const int lane = threadIdx.x & 63, wave = threadIdx.x >> 6;
    const int colv = lane & 15, g = lane >> 4;
    const int wm = wave & 1, wn = wave >> 1;
    __bf16* vn = vv + (size_t)n * 4096 * SS;
#pragma unroll
    for (int mt = 0; mt < 4; ++mt) {
      int o = m0 + wm * 64 + mt * 16 + g * 4;
      floatx4 bv = *(const floatx4*)&bias[o];
#pragma unroll
      for (int nt = 0; nt < 4; ++nt) {
        int s = n0 + wn * 64 + nt * 16 + colv;
#pragma unroll
        for (int i = 0; i < 4; ++i)
          vn[(size_t)(o + i - 4096) * SS + s] = (__bf16)(acc[mt][nt][i] + bv[i]);
      }
    }
  }
}

// ---------------- flash attention (PV d-split, DPP softmax, staged prefetch) ----------------
__global__ void __launch_bounds__(256) flash_attn(const __bf16* __restrict__ qT,
                                                  const __bf16* __restrict__ kT,
                                                  const __bf16* __restrict__ vv,
                                                  __bf16* __restrict__ yT) {
  const int n = blockIdx.z, h = blockIdx.y, qt = blockIdx.x;
  const int tid = threadIdx.x;
  const int wave = tid >> 6, lane = tid & 63;
  const int colv = lane & 15, g = lane >> 4;

  const __bf16* qTn = qT + (size_t)n * SS * 4096;
  const __bf16* kTn = kT + (size_t)n * SS * 4096;
  const __bf16* vn  = vv + (size_t)n * 4096 * SS;
  __bf16* yTn = yT + (size_t)n * SS * 4096;

  const int qrow0 = qt * 64 + wave * 16;

  __shared__ __bf16 kbuf[32 * 512];
  __shared__ __bf16 vbuf[512 * 32];
  __shared__ __bf16 pbuf[4 * 16 * 88];
  __shared__ float axs[64];
  __shared__ float ils[64];

  bf16x8 qf[16];
  {
    const __bf16* qp = qTn + (size_t)(qrow0 + colv) * 4096 + h * 512 + g * 8;
#pragma unroll
    for (int kc = 0; kc < 16; ++kc) qf[kc] = *(const bf16x8*)(qp + kc * 32);
  }

  floatx4 Oacc[32];
#pragma unroll
  for (int t = 0; t < 32; ++t) Oacc[t] = (floatx4)0.f;
  float mrun[4] = {-1e30f, -1e30f, -1e30f, -1e30f};
  float lrun[4] = {0.f, 0.f, 0.f, 0.f};

  __bf16* pb = pbuf + wave * (16 * 88);

  auto stageK = [&](int kt) {
    const int key0 = kt * 32;
#pragma unroll
    for (int j = 0; j < 8; ++j) {
      int row = wave * 8 + j;
      const __bf16* src = kTn + (size_t)(key0 + row) * 4096 + h * 512 + ((lane ^ (row & 7)) << 3);
      async16(src, &kbuf[row * 512]);
    }
  };
  auto stageV = [&](int kt) {
    const int key0 = kt * 32;
#pragma unroll
    for (int j = 0; j < 8; ++j) {
      int i = wave * 8 + j;
      int row = i * 16 + (lane >> 2);
      int ch = (lane & 3) ^ (row & 3);
      const __bf16* src = vn + (size_t)(h * 512 + row) * SS + key0 + ch * 8;
      async16(src, &vbuf[i * 16 * 32]);
    }
  };

  stageK(0);
  stageV(0);

  for (int kt = 0; kt < 64; ++kt) {
    __syncthreads();  // staged K/V drained & visible

    floatx4 sc[2];
    sc[0] = (floatx4)0.f;
    sc[1] = (floatx4)0.f;
#pragma unroll
    for (int ct = 0; ct < 2; ++ct) {
      int key = ct * 16 + colv;
      const __bf16* kb = &kbuf[key * 512];
      int sw = key & 7;
#pragma unroll
      for (int kc = 0; kc < 16; ++kc) {
        bf16x8 bfr = *(const bf16x8*)(kb + (((kc * 4 + g) ^ sw) << 3));
        sc[ct] = __builtin_amdgcn_mfma_f32_16x16x32_bf16(qf[kc], bfr, sc[ct], 0, 0, 0);
      }
    }

    float p[2][4], alpha[4];
#pragma unroll
    for (int i = 0; i < 4; ++i) {
      float mx = red_max16(fmaxf(sc[0][i], sc[1][i]));
      float mnew = fmaxf(mrun[i], mx * QK_SCALE);
      alpha[i] = __expf(mrun[i] - mnew);
      float rs = 0.f;
#pragma unroll
      for (int ct = 0; ct < 2; ++ct) {
        float pvv = __expf(sc[ct][i] * QK_SCALE - mnew);
        p[ct][i] = pvv;
        rs += pvv;
      }
      rs = red_sum16(rs);
      lrun[i] = lrun[i] * alpha[i] + rs;
      mrun[i] = mnew;
    }
#pragma unroll
    for (int ct = 0; ct < 2; ++ct)
#pragma unroll
      for (int i = 0; i < 4; ++i)
        pb[(g * 4 + i) * 88 + ct * 16 + colv] = (__bf16)p[ct][i];
    if (colv == 0) {
      floatx4 av;
#pragma unroll
      for (int i = 0; i < 4; ++i) av[i] = alpha[i];
      *(floatx4*)&axs[wave * 16 + g * 4] = av;
    }
    __syncthreads();  // P + alpha ready; kbuf reads done

    if (kt < 63) stageK(kt + 1);  // kbuf free during PV

#pragma unroll
    for (int qt4 = 0; qt4 < 4; ++qt4) {
      floatx4 av = *(const floatx4*)&axs[qt4 * 16 + g * 4];
#pragma unroll
      for (int dt = 0; dt < 8; ++dt) {
        floatx4 o = Oacc[qt4 * 8 + dt];
#pragma unroll
        for (int i = 0; i < 4; ++i) o[i] *= av[i];
        Oacc[qt4 * 8 + dt] = o;
      }
    }
    bf16x8 pa[4];
#pragma unroll
    for (int qt4 = 0; qt4 < 4; ++qt4)
      pa[qt4] = *(const bf16x8*)&pbuf[qt4 * (16 * 88) + colv * 88 + g * 8];
#pragma unroll
    for (int dt = 0; dt < 8; ++dt) {
      int drow = wave * 128 + dt * 16 + colv;
      bf16x8 vb = *(const bf16x8*)&vbuf[drow * 32 + ((g ^ (drow & 3)) << 3)];
#pragma unroll
      for (int qt4 = 0; qt4 < 4; ++qt4)
        Oacc[qt4 * 8 + dt] = __builtin_amdgcn_mfma_f32_16x16x32_bf16(pa[qt4], vb,
                                                                    Oacc[qt4 * 8 + dt], 0, 0, 0);
    }
    __syncthreads();  // PV reads done -> vbuf free
    if (kt < 63) stageV(kt + 1);
  }

  if (colv == 0) {
    floatx4 lv;
#pragma unroll
    for (int i = 0; i < 4; ++i) lv[i] = 1.f / lrun[i];
    *(floatx4*)&ils[wave * 16 + g * 4] = lv;
  }
  __syncthreads();
#pragma unroll
  for (int qt4 = 0; qt4 < 4; ++qt4) {
    floatx4 lv = *(const floatx4*)&ils[qt4 * 16 + g * 4];
#pragma unroll
    for (int dt = 0; dt < 8; ++dt)
#pragma unroll
      for (int i = 0; i < 4; ++i) {
        size_t idx = (size_t)(qt * 64 + qt4 * 16 + g * 4 + i) * 4096 + h * 512 + wave * 128 +
                     dt * 16 + colv;
        yTn[idx] = (__bf16)(Oacc[qt4 * 8 + dt][i] * lv[i]);
      }
  }
}

// ---------------- fused out GEMM: out[c][s] = input + bo[c] + Wo·y ----------------
// A = WoB (M=512=c rows, K=4096), Bt = yT (N=2048=s rows, K=4096).
// Tile 128(c) x 64(s); 4 waves each own a 32-row c-slice; stores are
// s-contiguous fp32 (natively coalesced) -> no partials, no combine pass.
__global__ void __launch_bounds__(256) gemm_out_fused(const __bf16* __restrict__ Wo,
                                                      const __bf16* __restrict__ yT,
                                                      const float* __restrict__ bo,
                                                      const float* __restrict__ input,
                                                      float* __restrict__ out) {
  __shared__ __bf16 lA[128 * 64], lB[64 * 64];
  const int n = blockIdx.z;
  const int m0 = blockIdx.x * 128, n0 = blockIdx.y * 64;
  const __bf16* Bt = yT + (size_t)n * SS * 4096;
  const int tid = threadIdx.x;
  const int wave = tid >> 6, lane = tid & 63;
  const int colv = lane & 15, g = lane >> 4;
  const int lrow = lane >> 3, lch = lane & 7;

  floatx4 acc[2][4];
#pragma unroll
  for (int mt = 0; mt < 2; ++mt)
#pragma unroll
    for (int nt = 0; nt < 4; ++nt) acc[mt][nt] = (floatx4)0.f;

  for (int k0 = 0; k0 < 4096; k0 += 64) {
    __syncthreads();
#pragma unroll
    for (int j = 0; j < 4; ++j) {  // A: 128 rows, 4 instr/wave
      int r = wave * 32 + j * 8 + lrow;
      int ch = lch ^ (r & 7);
      async16(Wo + (size_t)(m0 + r) * 4096 + k0 + ch * 8, &lA[(wave * 32 + j * 8) * 64]);
    }
#pragma unroll
    for (int j = 0; j < 2; ++j) {  // B: 64 rows, 2 instr/wave
      int r = wave * 16 + j * 8 + lrow;
      int ch = lch ^ (r & 7);
      async16(Bt + (size_t)(n0 + r) * 4096 + k0 + ch * 8, &lB[(wave * 16 + j * 8) * 64]);
    }
    __syncthreads();
#pragma unroll
    for (int c = 0; c < 2; ++c) {
      bf16x8 af[2], bf[4];
#pragma unroll
      for (int t = 0; t < 2; ++t) {
        int r = wave * 32 + t * 16 + colv;
        af[t] = *(const bf16x8*)&lA[r * 64 + (((c * 4 + g) ^ (r & 7)) << 3)];
      }
#pragma unroll
      for (int t = 0; t < 4; ++t) {
        int rb = t * 16 + colv;
        bf[t] = *(const bf16x8*)&lB[rb * 64 + (((c * 4 + g) ^ (rb & 7)) << 3)];
      }
#pragma unroll
      for (int mt = 0; mt < 2; ++mt)
#pragma unroll
        for (int nt = 0; nt < 4; ++nt)
          acc[mt][nt] = __builtin_amdgcn_mfma_f32_16x16x32_bf16(af[mt], bf[nt], acc[mt][nt], 0, 0, 0);
    }
  }
  // epilogue: c = m0+wave*32+mt*16+g*4+i ; s = n0+nt*16+colv ; fp32 direct
#pragma unroll
  for (int mt = 0; mt < 2; ++mt) {
#pragma unroll
    for (int i = 0; i < 4; ++i) {
      int c = m0 + wave * 32 + mt * 16 + g * 4 + i;
      float bov = bo[c];
      size_t rowb = ((size_t)n * CC + c) * SS;
#pragma unroll
      for (int nt = 0; nt < 4; ++nt) {
        int s = n0 + nt * 16 + colv;
        out[rowb + s] = acc[mt][nt][i] + bov + input[rowb + s];
      }
    }
  }
}

// ---------------- host launcher ----------------
extern "C" void kernel_launch(void* const* d_in, const int* in_sizes, int n_in,
                              void* d_out, int out_size, void* d_ws, size_t ws_size,
                              hipStream_t stream) {
  const float* input   = (const float*)d_in[0];
  const float* context = (const float*)d_in[1];
  const float* gamma   = (const float*)d_in[2];
  const float* beta    = (const float*)d_in[3];
  const float* Wq      = (const float*)d_in[4];
  const float* bq      = (const float*)d_in[5];
  const float* Wkv     = (const float*)d_in[6];
  const float* bkv     = (const float*)d_in[7];
  const float* Wo      = (const float*)d_in[8];
  const float* bo      = (const float*)d_in[9];
  float* out = (float*)d_out;
  (void)in_sizes; (void)n_in; (void)out_size;

  char* ws = (char*)d_ws;
  size_t off = 0;
  auto alloc = [&](size_t b) {
    void* p = ws + off;
    off = (off + b + 255) & ~(size_t)255;
    return p;
  };
  float*  lnp  = (float*)alloc((size_t)4 * 128 * 2 * sizeof(float));
  float*  muA  = (float*)alloc(4 * sizeof(float));
  float*  rsA  = (float*)alloc(4 * sizeof(float));
  __bf16* WqB  = (__bf16*)alloc((size_t)4096 * 512 * 2);
  __bf16* WkvB = (__bf16*)alloc((size_t)8192 * 512 * 2);
  __bf16* WoB  = (__bf16*)alloc((size_t)512 * 4096 * 2);
  __bf16* xnT  = (__bf16*)alloc((size_t)NB * SS * CC * 2);
  __bf16* ctxT = (__bf16*)alloc((size_t)NB * SS * CC * 2);

  const size_t PB = (size_t)SS * 4096 * 2;  // 16 MB per batch of q/k/v/y

  prep1<<<dim3(512 + 3 * 4096), dim3(256), 0, stream>>>(input, lnp, Wq, WqB, Wkv, WkvB, Wo, WoB);
  ln_final<<<dim3(4), dim3(128), 0, stream>>>(lnp, muA, rsA);
  transpose_nc<<<dim3(64, 16, 8), dim3(32, 8), 0, stream>>>(input, context, xnT, ctxT, muA, rsA,
                                                            gamma, beta);

  const size_t MiB = 1ull << 20;
  if (ws_size >= off + 16 * PB + 8 * MiB) {
    // Path A: full-batch buffers
    __bf16* qTb = (__bf16*)alloc(NB * PB);
    __bf16* kTb = (__bf16*)alloc(NB * PB);
    __bf16* vB  = (__bf16*)alloc(NB * PB);
    __bf16* yTb = (__bf16*)alloc(NB * PB);
    gemm_qkv<<<dim3(96, 16, 4), dim3(256), 0, stream>>>(WqB, WkvB, xnT, ctxT, bq, bkv, qTb, kTb,
                                                        vB);
    flash_attn<<<dim3(32, 8, 4), dim3(256), 0, stream>>>(qTb, kTb, vB, yTb);
    gemm_out_fused<<<dim3(4, 32, 4), dim3(256), 0, stream>>>(WoB, yTb, bo, input, out);
  } else if (ws_size >= off + 7 * PB + 8 * MiB) {
    // Path B: per-batch q/k/v, full yT
    __bf16* qTb = (__bf16*)alloc(PB);
    __bf16* kTb = (__bf16*)alloc(PB);
    __bf16* vB  = (__bf16*)alloc(PB);
    __bf16* yTb = (__bf16*)alloc(NB * PB);
    for (int n = 0; n < NB; ++n) {
      gemm_qkv<<<dim3(96, 16, 1), dim3(256), 0, stream>>>(WqB, WkvB, xnT + (size_t)n * SS * CC,
                                                          ctxT + (size_t)n * SS * CC, bq, bkv,
                                                          qTb, kTb, vB);
      flash_attn<<<dim3(32, 8, 1), dim3(256), 0, stream>>>(qTb, kTb, vB,
                                                           yTb + (size_t)n * SS * 4096);
    }
    gemm_out_fused<<<dim3(4, 32, 4), dim3(256), 0, stream>>>(WoB, yTb, bo, input, out);
  } else {
    // Path C: everything per-batch
    __bf16* qTb = (__bf16*)alloc(PB);
    __bf16* kTb = (__bf16*)alloc(PB);
    __bf16* vB  = (__bf16*)alloc(PB);
    __bf16* yTb = (__bf16*)alloc(PB);
    for (int n = 0; n < NB; ++n) {
      gemm_qkv<<<dim3(96, 16, 1), dim3(256), 0, stream>>>(WqB, WkvB, xnT + (size_t)n * SS * CC,
                                                          ctxT + (size_t)n * SS * CC, bq, bkv,
                                                          qTb, kTb, vB);
      flash_attn<<<dim3(32, 8, 1), dim3(256), 0, stream>>>(qTb, kTb, vB, yTb);
      gemm_out_fused<<<dim3(4, 32, 1), dim3(256), 0, stream>>>(WoB, yTb, bo,
                                                               input + (size_t)n * CC * SS,
                                                               out + (size_t)n * CC * SS);
    }
  }
}